// Round 1
// baseline (8163.309 us; speedup 1.0000x reference)
//
#include <hip/hip_runtime.h>
#include <math.h>

// ---------------- problem constants ----------------
constexpr int NB   = 4096;   // B
constexpr int NU   = 6;      // U
constexpr int NIN  = 256;    // IN
constexpr int NH   = 600;    // H
constexpr int IKS  = 64;
constexpr int IVS  = 400;
constexpr int NCH  = 4;
constexpr int CVS  = 600;
constexpr int KTOP = 4;

constexpr int KVW  = IKS + IVS;      // 464 (key0 | val0)
constexpr int G3H  = 3 * NH;         // 1800
constexpr int QKW  = 256;            // q(128) | k(128)
constexpr int VW   = NCH * CVS;      // 2400

// chunking for stage C scratch
constexpr int BC     = 512;
constexpr int NCHUNK = NB / BC;      // 8

// ---------------- ws layout (float offsets) ----------------
constexpr long OFF_KV   = 0;                                  // [NB][464]
constexpr long OFF_QRY  = OFF_KV   + (long)NB * KVW;          // [NB][NU][64]
constexpr long OFF_C0   = OFF_QRY  + (long)NB * NU * IKS;     // [NB][NU]
constexpr long OFF_C1   = OFF_C0   + (long)NB * NU;
constexpr long OFF_MASK = OFF_C1   + (long)NB * NU;
constexpr long OFF_HNEW = OFF_MASK + (long)NB * NU;           // [NB][NU][600]
constexpr long OFF_QK   = OFF_HNEW + (long)NB * NU * NH;      // [NB][NU][256]
constexpr long OFF_ATTW = OFF_QK   + (long)NB * NU * QKW;     // [NB][NCH][NU][NU]
constexpr long OFF_VBUF = OFF_ATTW + (long)NB * NCH * NU * NU;// [BC][NU][2400]
constexpr long OFF_CTX  = OFF_VBUF + (long)BC * NU * VW;      // [BC][NU][2400]
// total ~ 39.9M floats ~ 160 MB

// ================= generic per-u GEMM =================
// C[row, u, cofs+c] = sum_k A[row*lda + u*K + k] * W[u*wstride + k*N + c]
__global__ __launch_bounds__(256)
void gemm_bu_kernel(const float* __restrict__ A, long lda,
                    const float* __restrict__ W, long wstride,
                    float* __restrict__ C, long ldc, int cu, int cofs,
                    int K, int N)
{
    const int u  = blockIdx.z;
    const int m0 = blockIdx.x * 64;
    const int n0 = blockIdx.y * 64;
    const int tid = threadIdx.x;
    const int tm = tid / 16;   // 0..15 -> rows tm*4..tm*4+3
    const int tn = tid % 16;   // 0..15 -> cols tn*4..tn*4+3

    __shared__ __align__(16) float As[16][72];
    __shared__ __align__(16) float Ws[16][72];

    const float* Au = A + (long)u * K;
    const float* Wu = W + (long)u * wstride;

    float acc[4][4] = {};

    for (int k0 = 0; k0 < K; k0 += 16) {
        // stage A (transposed): thread t loads 4 rows at col kk
        {
            int kk = tid % 16;
            int mb = (tid / 16) * 4;
            float v0 = 0, v1 = 0, v2 = 0, v3 = 0;
            if (k0 + kk < K) {
                long col = k0 + kk;
                v0 = Au[(long)(m0 + mb + 0) * lda + col];
                v1 = Au[(long)(m0 + mb + 1) * lda + col];
                v2 = Au[(long)(m0 + mb + 2) * lda + col];
                v3 = Au[(long)(m0 + mb + 3) * lda + col];
            }
            As[kk][mb + 0] = v0; As[kk][mb + 1] = v1;
            As[kk][mb + 2] = v2; As[kk][mb + 3] = v3;
        }
        // stage W: thread t loads col c at 4 k's
        {
            int c  = tid % 64;
            int kq = tid / 64;
            #pragma unroll
            for (int q = 0; q < 4; q++) {
                int kk = kq + q * 4;
                float v = 0;
                if (k0 + kk < K && n0 + c < N)
                    v = Wu[(long)(k0 + kk) * N + n0 + c];
                Ws[kk][c] = v;
            }
        }
        __syncthreads();
        #pragma unroll
        for (int kk = 0; kk < 16; kk++) {
            float4 a4 = *(const float4*)&As[kk][tm * 4];
            float4 w4 = *(const float4*)&Ws[kk][tn * 4];
            float av[4] = {a4.x, a4.y, a4.z, a4.w};
            float wv[4] = {w4.x, w4.y, w4.z, w4.w};
            #pragma unroll
            for (int i = 0; i < 4; i++)
                #pragma unroll
                for (int j = 0; j < 4; j++)
                    acc[i][j] = fmaf(av[i], wv[j], acc[i][j]);
        }
        __syncthreads();
    }
    #pragma unroll
    for (int i = 0; i < 4; i++) {
        int row = m0 + tm * 4 + i;
        #pragma unroll
        for (int j = 0; j < 4; j++) {
            int c = n0 + tn * 4 + j;
            if (c < N)
                C[(long)row * ldc + (long)u * cu + cofs + c] = acc[i][j];
        }
    }
}

// ================= G1: kv = x @ [Wk|Wv] + [bk|bv] =================
__global__ __launch_bounds__(256)
void gemm_kv_kernel(const float* __restrict__ x,
                    const float* __restrict__ Wk, const float* __restrict__ bk,
                    const float* __restrict__ Wv, const float* __restrict__ bv,
                    float* __restrict__ kvout)
{
    const int m0 = blockIdx.x * 64;
    const int n0 = blockIdx.y * 64;
    const int tid = threadIdx.x;
    const int tm = tid / 16;
    const int tn = tid % 16;
    constexpr int K = NIN;   // 256
    constexpr int N = KVW;   // 464

    __shared__ __align__(16) float As[16][72];
    __shared__ __align__(16) float Ws[16][72];

    float acc[4][4] = {};

    for (int k0 = 0; k0 < K; k0 += 16) {
        {
            int kk = tid % 16;
            int mb = (tid / 16) * 4;
            long col = k0 + kk;
            As[kk][mb + 0] = x[(long)(m0 + mb + 0) * K + col];
            As[kk][mb + 1] = x[(long)(m0 + mb + 1) * K + col];
            As[kk][mb + 2] = x[(long)(m0 + mb + 2) * K + col];
            As[kk][mb + 3] = x[(long)(m0 + mb + 3) * K + col];
        }
        {
            int c  = tid % 64;
            int kq = tid / 64;
            #pragma unroll
            for (int q = 0; q < 4; q++) {
                int kk = kq + q * 4;
                int cg = n0 + c;
                float v = 0;
                if (cg < IKS)      v = Wk[(long)(k0 + kk) * IKS + cg];
                else if (cg < N)   v = Wv[(long)(k0 + kk) * IVS + (cg - IKS)];
                Ws[kk][c] = v;
            }
        }
        __syncthreads();
        #pragma unroll
        for (int kk = 0; kk < 16; kk++) {
            float4 a4 = *(const float4*)&As[kk][tm * 4];
            float4 w4 = *(const float4*)&Ws[kk][tn * 4];
            float av[4] = {a4.x, a4.y, a4.z, a4.w};
            float wv[4] = {w4.x, w4.y, w4.z, w4.w};
            #pragma unroll
            for (int i = 0; i < 4; i++)
                #pragma unroll
                for (int j = 0; j < 4; j++)
                    acc[i][j] = fmaf(av[i], wv[j], acc[i][j]);
        }
        __syncthreads();
    }
    #pragma unroll
    for (int i = 0; i < 4; i++) {
        int row = m0 + tm * 4 + i;
        #pragma unroll
        for (int j = 0; j < 4; j++) {
            int cg = n0 + tn * 4 + j;
            if (cg < N) {
                float bias = (cg < IKS) ? bk[cg] : bv[cg - IKS];
                kvout[(long)row * N + cg] = acc[i][j] + bias;
            }
        }
    }
}

// ================= K3: scores / top-k mask / probs =================
__global__ __launch_bounds__(64)
void score_kernel(const float* __restrict__ qry,   // [NB][NU][64]
                  const float* __restrict__ kv,    // [NB][464]
                  const float* __restrict__ bk,    // [64]
                  float* __restrict__ c0, float* __restrict__ c1,
                  float* __restrict__ maskf)
{
    const int b = blockIdx.x;
    const int t = threadIdx.x;
    __shared__ float s0s[NU], s1s[NU];

    float k0v = kv[(long)b * KVW + t];
    float bkv = bk[t];
    for (int u = 0; u < NU; u++) {
        float q  = qry[((long)b * NU + u) * IKS + t];
        float p0 = q * k0v;
        float p1 = q * bkv;
        #pragma unroll
        for (int off = 32; off > 0; off >>= 1) {
            p0 += __shfl_down(p0, off);
            p1 += __shfl_down(p1, off);
        }
        if (t == 0) { s0s[u] = p0 * 0.125f; s1s[u] = p1 * 0.125f; }
    }
    __syncthreads();
    if (t < NU) {
        int u = t;
        float su = s0s[u];
        int rank = 0;
        #pragma unroll
        for (int j = 0; j < NU; j++) {
            float sj = s0s[j];
            if (sj > su || (sj == su && j < u)) rank++;
        }
        float m = (rank < KTOP) ? 1.0f : 0.0f;
        float a = s0s[u], bb = s1s[u];
        float mx = fmaxf(a, bb);
        float e0 = expf(a - mx), e1 = expf(bb - mx);
        float p0 = e0 / (e0 + e1);
        c0[(long)b * NU + u]    = m * p0;
        c1[(long)b * NU + u]    = m * (1.0f - p0);
        maskf[(long)b * NU + u] = m;
    }
}

// ================= G4: fused gx+gh+GRU -> hnew =================
__global__ __launch_bounds__(256)
void gru_kernel(const float* __restrict__ kv,   // [NB][464], val0 at +64
                const float* __restrict__ bv,   // [400]
                const float* __restrict__ hs,   // [NB][NU][600]
                const float* __restrict__ x2h,  // [NU][400][1800]
                const float* __restrict__ h2h,  // [NU][600][1800]
                const float* __restrict__ c0,
                const float* __restrict__ c1,
                float* __restrict__ hnew)
{
    const int u  = blockIdx.z;
    const int m0 = blockIdx.x * 32;
    const int n0 = blockIdx.y * 32;
    const int tid = threadIdx.x;
    const int tm = tid / 16;   // rows tm*2, tm*2+1
    const int tn = tid % 16;   // cols tn*2, tn*2+1

    __shared__ __align__(16) float As[16][36];
    __shared__ __align__(16) float Ws[16][100];
    __shared__ float cf0[32], cf1[32];

    if (tid < 32) {
        cf0[tid] = c0[(long)(m0 + tid) * NU + u];
        cf1[tid] = c1[(long)(m0 + tid) * NU + u];
    }
    __syncthreads();

    float ar[2][2] = {}, ai[2][2] = {}, axn[2][2] = {}, ahn[2][2] = {};

    #pragma unroll
    for (int ph = 0; ph < 2; ph++) {
        const int K = ph ? NH : IVS;   // 600 : 400
        const float* Wp = ph ? (h2h + (long)u * NH * G3H)
                             : (x2h + (long)u * IVS * G3H);
        for (int k0 = 0; k0 < K; k0 += 16) {
            #pragma unroll
            for (int p = 0; p < 2; p++) {
                int i = tid + p * 256;
                int kk = i % 16, m = i / 16;
                int k = k0 + kk;
                float v = 0;
                if (k < K) {
                    int b = m0 + m;
                    if (ph == 0)
                        v = cf0[m] * kv[(long)b * KVW + IKS + k] + cf1[m] * bv[k];
                    else
                        v = hs[((long)b * NU + u) * NH + k];
                }
                As[kk][m] = v;
            }
            #pragma unroll
            for (int p = 0; p < 6; p++) {
                int i = tid + p * 256;
                int kk = i / 96, cj = i % 96;
                int g = cj / 32, cc = cj % 32;
                int k = k0 + kk, c = n0 + cc;
                float v = 0;
                if (k < K && c < NH)
                    v = Wp[(long)k * G3H + g * NH + c];
                Ws[kk][cj] = v;
            }
            __syncthreads();
            #pragma unroll
            for (int kk = 0; kk < 16; kk++) {
                float2 a2 = *(const float2*)&As[kk][tm * 2];
                float2 wr = *(const float2*)&Ws[kk][tn * 2];
                float2 wi = *(const float2*)&Ws[kk][32 + tn * 2];
                float2 wn = *(const float2*)&Ws[kk][64 + tn * 2];
                float av[2] = {a2.x, a2.y};
                float wrv[2] = {wr.x, wr.y};
                float wiv[2] = {wi.x, wi.y};
                float wnv[2] = {wn.x, wn.y};
                #pragma unroll
                for (int i = 0; i < 2; i++)
                    #pragma unroll
                    for (int j = 0; j < 2; j++) {
                        ar[i][j] = fmaf(av[i], wrv[j], ar[i][j]);
                        ai[i][j] = fmaf(av[i], wiv[j], ai[i][j]);
                        if (ph == 0) axn[i][j] = fmaf(av[i], wnv[j], axn[i][j]);
                        else         ahn[i][j] = fmaf(av[i], wnv[j], ahn[i][j]);
                    }
            }
            __syncthreads();
        }
    }
    #pragma unroll
    for (int i = 0; i < 2; i++) {
        int b = m0 + tm * 2 + i;
        #pragma unroll
        for (int j = 0; j < 2; j++) {
            int c = n0 + tn * 2 + j;
            if (c < NH) {
                float h  = hs[((long)b * NU + u) * NH + c];
                float rg = 1.0f / (1.0f + expf(-ar[i][j]));
                float ig = 1.0f / (1.0f + expf(-ai[i][j]));
                float ng = tanhf(axn[i][j] + rg * ahn[i][j]);
                hnew[((long)b * NU + u) * NH + c] = ng + ig * (h - ng);
            }
        }
    }
}

// ================= K7: attention weights =================
__global__ __launch_bounds__(64)
void attw_kernel(const float* __restrict__ qk,     // [NB][NU][256]
                 const float* __restrict__ maskf,  // [NB][NU]
                 float* __restrict__ attw)         // [NB][NCH][NU][NU]
{
    const int bh = blockIdx.x;
    const int b = bh / NCH, h = bh % NCH;
    const int t = threadIdx.x;
    __shared__ float lg[NU][NU];

    if (t < NU * NU) {
        int uq = t / NU, un = t % NU;
        const float* qp = qk + ((long)b * NU + uq) * QKW + h * 32;
        const float* kp = qk + ((long)b * NU + un) * QKW + 128 + h * 32;
        float s = 0;
        #pragma unroll
        for (int i = 0; i < 32; i++) s = fmaf(qp[i], kp[i], s);
        lg[uq][un] = s * 0.17677669529663687f;   // 1/sqrt(32)
    }
    __syncthreads();
    if (t < NU) {
        int uq = t;
        float mx = -1e30f;
        #pragma unroll
        for (int n = 0; n < NU; n++) mx = fmaxf(mx, lg[uq][n]);
        float e[NU], se = 0;
        #pragma unroll
        for (int n = 0; n < NU; n++) { e[n] = expf(lg[uq][n] - mx); se += e[n]; }
        float m = maskf[(long)b * NU + uq];
        float inv = m / se;
        #pragma unroll
        for (int n = 0; n < NU; n++)
            attw[(((long)b * NCH + h) * NU + uq) * NU + n] = e[n] * inv;
    }
}

// ================= K_ctx: ctx = att @ v (per head chunk) =================
__global__ __launch_bounds__(256)
void ctx_kernel(const float* __restrict__ attw, const float* __restrict__ vbuf,
                float* __restrict__ ctx, int bbase)
{
    long idx = (long)blockIdx.x * 256 + threadIdx.x;
    const long total = (long)BC * NU * VW;
    if (idx >= total) return;
    int c  = (int)(idx % VW);
    int uu = (int)((idx / VW) % NU);
    int bl = (int)(idx / ((long)VW * NU));
    int b  = bbase + bl;
    int h  = c / CVS;
    const float* aw = attw + (((long)b * NCH + h) * NU + uu) * NU;
    const float* vp = vbuf + (long)bl * NU * VW + c;
    float s = 0;
    #pragma unroll
    for (int n = 0; n < NU; n++) s = fmaf(aw[n], vp[(long)n * VW], s);
    ctx[idx] = s;
}

// ================= G8: out = mask ? (ctx@Wout + hnew) : h_old =================
__global__ __launch_bounds__(256)
void gemm_out_kernel(const float* __restrict__ A,     // ctx chunk [BC][NU][2400]
                     const float* __restrict__ W,     // Wout [NU][2400][600]
                     const float* __restrict__ hnew,
                     const float* __restrict__ hs,
                     const float* __restrict__ maskf,
                     float* __restrict__ out,
                     int bbase)
{
    const int u  = blockIdx.z;
    const int m0 = blockIdx.x * 64;
    const int n0 = blockIdx.y * 64;
    const int tid = threadIdx.x;
    const int tm = tid / 16;
    const int tn = tid % 16;
    constexpr int K = VW;   // 2400
    constexpr int N = NH;   // 600

    __shared__ __align__(16) float As[16][72];
    __shared__ __align__(16) float Ws[16][72];

    const float* Au = A + (long)u * K;
    const float* Wu = W + (long)u * K * N;

    float acc[4][4] = {};

    for (int k0 = 0; k0 < K; k0 += 16) {
        {
            int kk = tid % 16;
            int mb = (tid / 16) * 4;
            long col = k0 + kk;
            As[kk][mb + 0] = Au[(long)(m0 + mb + 0) * (NU * VW) + col];
            As[kk][mb + 1] = Au[(long)(m0 + mb + 1) * (NU * VW) + col];
            As[kk][mb + 2] = Au[(long)(m0 + mb + 2) * (NU * VW) + col];
            As[kk][mb + 3] = Au[(long)(m0 + mb + 3) * (NU * VW) + col];
        }
        {
            int c  = tid % 64;
            int kq = tid / 64;
            #pragma unroll
            for (int q = 0; q < 4; q++) {
                int kk = kq + q * 4;
                float v = 0;
                if (n0 + c < N) v = Wu[(long)(k0 + kk) * N + n0 + c];
                Ws[kk][c] = v;
            }
        }
        __syncthreads();
        #pragma unroll
        for (int kk = 0; kk < 16; kk++) {
            float4 a4 = *(const float4*)&As[kk][tm * 4];
            float4 w4 = *(const float4*)&Ws[kk][tn * 4];
            float av[4] = {a4.x, a4.y, a4.z, a4.w};
            float wv[4] = {w4.x, w4.y, w4.z, w4.w};
            #pragma unroll
            for (int i = 0; i < 4; i++)
                #pragma unroll
                for (int j = 0; j < 4; j++)
                    acc[i][j] = fmaf(av[i], wv[j], acc[i][j]);
        }
        __syncthreads();
    }
    #pragma unroll
    for (int i = 0; i < 4; i++) {
        int row = m0 + tm * 4 + i;
        int gb  = bbase + row;
        #pragma unroll
        for (int j = 0; j < 4; j++) {
            int c = n0 + tn * 4 + j;
            if (c < N) {
                long o = ((long)gb * NU + u) * NH + c;
                float m   = maskf[(long)gb * NU + u];
                float val = acc[i][j] + hnew[o];
                out[o] = (m > 0.5f) ? val : hs[o];
            }
        }
    }
}

// ================= host launcher =================
extern "C" void kernel_launch(void* const* d_in, const int* in_sizes, int n_in,
                              void* d_out, int out_size, void* d_ws, size_t ws_size,
                              hipStream_t stream)
{
    const float* x    = (const float*)d_in[0];
    const float* hs   = (const float*)d_in[1];
    const float* Wk   = (const float*)d_in[2];
    const float* bk   = (const float*)d_in[3];
    const float* Wv   = (const float*)d_in[4];
    const float* bv   = (const float*)d_in[5];
    const float* Wq   = (const float*)d_in[6];
    const float* x2h  = (const float*)d_in[7];
    const float* h2h  = (const float*)d_in[8];
    const float* Wq_  = (const float*)d_in[9];
    const float* Wk_  = (const float*)d_in[10];
    const float* Wv_  = (const float*)d_in[11];
    const float* Wout = (const float*)d_in[12];
    float* out = (float*)d_out;
    float* ws  = (float*)d_ws;

    float* kv    = ws + OFF_KV;
    float* qry   = ws + OFF_QRY;
    float* c0b   = ws + OFF_C0;
    float* c1b   = ws + OFF_C1;
    float* maskf = ws + OFF_MASK;
    float* hnew  = ws + OFF_HNEW;
    float* qk    = ws + OFF_QK;
    float* attw  = ws + OFF_ATTW;
    float* vbuf  = ws + OFF_VBUF;
    float* ctxb  = ws + OFF_CTX;

    // G1: kv = x @ [Wk|Wv] + bias
    gemm_kv_kernel<<<dim3(NB / 64, (KVW + 63) / 64), 256, 0, stream>>>(
        x, Wk, bk, Wv, bv, kv);

    // G2: qry = hs @ Wq  (per u), N=64
    gemm_bu_kernel<<<dim3(NB / 64, 1, NU), 256, 0, stream>>>(
        hs, (long)NU * NH, Wq, (long)NH * IKS, qry, (long)NU * IKS, IKS, 0, NH, IKS);

    // K3: scores -> mask, coef0/coef1
    score_kernel<<<NB, 64, 0, stream>>>(qry, kv, bk, c0b, c1b, maskf);

    // G4: fused gx+gh+GRU -> hnew
    gru_kernel<<<dim3(NB / 32, (NH + 31) / 32, NU), 256, 0, stream>>>(
        kv, bv, hs, x2h, h2h, c0b, c1b, hnew);

    // G5: q and k projections into qk
    gemm_bu_kernel<<<dim3(NB / 64, 2, NU), 256, 0, stream>>>(
        hnew, (long)NU * NH, Wq_, (long)NH * 128, qk, (long)NU * QKW, QKW, 0, NH, 128);
    gemm_bu_kernel<<<dim3(NB / 64, 2, NU), 256, 0, stream>>>(
        hnew, (long)NU * NH, Wk_, (long)NH * 128, qk, (long)NU * QKW, QKW, 128, NH, 128);

    // K7: attention weights
    attw_kernel<<<NB * NCH, 64, 0, stream>>>(qk, maskf, attw);

    // stage C in chunks of BC rows
    for (int ch = 0; ch < NCHUNK; ch++) {
        const float* hloc = hnew + (long)ch * BC * NU * NH;
        // v = hnew @ Wv_ (per u), N=2400
        gemm_bu_kernel<<<dim3(BC / 64, (VW + 63) / 64, NU), 256, 0, stream>>>(
            hloc, (long)NU * NH, Wv_, (long)NH * VW, vbuf, (long)NU * VW, VW, 0, NH, VW);
        // ctx = att @ v
        long tot = (long)BC * NU * VW;
        ctx_kernel<<<(unsigned)((tot + 255) / 256), 256, 0, stream>>>(
            attw, vbuf, ctxb, ch * BC);
        // out = mask ? ctx@Wout + hnew : h_old
        gemm_out_kernel<<<dim3(BC / 64, (NH + 63) / 64, NU), 256, 0, stream>>>(
            ctxb, Wout, hnew, hs, maskf, out, ch * BC);
    }
}

// Round 2
// 1735.189 us; speedup vs baseline: 4.7046x; 4.7046x over previous
//
#include <hip/hip_runtime.h>
#include <math.h>

typedef unsigned short u16;
typedef __attribute__((ext_vector_type(8))) short short8;
typedef __attribute__((ext_vector_type(4))) float f32x4;

// ---------------- problem constants ----------------
constexpr int NB   = 4096;   // B
constexpr int NU   = 6;      // U
constexpr int NIN  = 256;    // IN
constexpr int NH   = 600;    // H
constexpr int IKS  = 64;
constexpr int IVS  = 400;
constexpr int NCH  = 4;
constexpr int CVS  = 600;
constexpr int KTOP = 4;

constexpr int KVW  = IKS + IVS;      // 464
constexpr int QKW  = 256;            // q(128)|k(128)
constexpr int VW   = NCH * CVS;      // 2400

// padded MFMA dims
constexpr int KGRU = 1024;           // [inputs 0..399 |0| hs 416..1015 |0]
constexpr int HOFS = 416;            // hs starts here (13*32)
constexpr int NGATE = 640;           // 600 padded
constexpr int KH   = 640;            // hnew K padded (600->640)
constexpr int VN   = 2432;           // 2400 padded (19*128)
constexpr int BC   = 512;
constexpr int NCHUNK = NB / BC;      // 8

// ---------------- ws layout (float offsets) ----------------
constexpr long OFF_KV   = 0;                                   // f32 [NB][464]
constexpr long OFF_QRY  = OFF_KV   + (long)NB * KVW;           // f32 [NB][NU][64]
constexpr long OFF_C0   = OFF_QRY  + (long)NB * NU * IKS;
constexpr long OFF_C1   = OFF_C0   + (long)NB * NU;
constexpr long OFF_MASK = OFF_C1   + (long)NB * NU;
constexpr long OFF_QK   = OFF_MASK + (long)NB * NU;            // f32 [NB][NU][256]
constexpr long OFF_ATTW = OFF_QK   + (long)NB * NU * QKW;      // f32 [NB][NCH][NU][NU]
constexpr long OFF_HNBF = OFF_ATTW + (long)NB * NCH * NU * NU; // bf16 [NU][NB][640]
constexpr long OFF_WQK  = OFF_HNBF + (long)NU * NB * KH / 2;   // bf16 [NU][256][640]
constexpr long OFF_WV   = OFF_WQK  + (long)NU * QKW * KH / 2;  // bf16 [NU][2432][640]
constexpr long OFF_WOUT = OFF_WV   + (long)NU * VN * KH / 2;   // bf16 [NU][640][2432]
constexpr long OFF_WGRU = OFF_WOUT + (long)NU * NGATE * VN / 2;// bf16 [NU][3][640][1024]
constexpr long OFF_AGRU = OFF_WGRU + (long)NU * 3 * NGATE * KGRU / 2; // bf16 [NU][NB][1024]
// aliased into AGRU region after GRU GEMM:
constexpr long OFF_VBUF = OFF_AGRU;                            // f32 [BC][NU][2432]
constexpr long OFF_CTXB = OFF_VBUF + (long)BC * NU * VN;       // bf16 [BC][NU][2432]
// zero-fill region: all bf16 weight buffers
constexpr long ZF_OFF = OFF_WQK;
constexpr long ZF_N4  = (OFF_AGRU - OFF_WQK) / 4;

// ---------------- helpers ----------------
__device__ __forceinline__ u16 f2bf(float f) {
    unsigned int x = __float_as_uint(f);
    x += 0x7FFFu + ((x >> 16) & 1u);
    return (u16)(x >> 16);
}
__device__ __forceinline__ float bf2f(u16 u) {
    return __uint_as_float(((unsigned int)u) << 16);
}
__device__ __forceinline__ void gl_lds16(const u16* g, u16* l) {
    __builtin_amdgcn_global_load_lds(
        (const __attribute__((address_space(1))) void*)g,
        (__attribute__((address_space(3))) void*)l, 16, 0, 0);
}

// ================= zero fill =================
__global__ __launch_bounds__(256)
void zfill_kernel(float4* __restrict__ p, long n4)
{
    long i = (long)blockIdx.x * 256 + threadIdx.x;
    long stride = (long)gridDim.x * 256;
    float4 z = {0.f, 0.f, 0.f, 0.f};
    for (; i < n4; i += stride) p[i] = z;
}

// ================= weight transpose f32[K][N] -> bf16[n][k] =================
__global__ __launch_bounds__(256)
void wtrans_kernel(const float* __restrict__ src, long s_u, int s_ld, int s_colofs,
                   int Ksrc, int Nsub,
                   u16* __restrict__ dst, long d_u, int d_ld, int d_nofs, int d_kofs)
{
    __shared__ float tile[32][33];
    const int u  = blockIdx.z;
    const int k0 = blockIdx.x * 32, n0 = blockIdx.y * 32;
    const int t  = threadIdx.x;
    const float* S = src + (long)u * s_u;
    u16* D = dst + (long)u * d_u;
    #pragma unroll
    for (int r = 0; r < 4; r++) {
        int kk = r * 8 + (t >> 5), nn = t & 31;
        float v = 0.f;
        if (k0 + kk < Ksrc && n0 + nn < Nsub)
            v = S[(long)(k0 + kk) * s_ld + s_colofs + n0 + nn];
        tile[kk][nn] = v;
    }
    __syncthreads();
    #pragma unroll
    for (int r = 0; r < 4; r++) {
        int nn = r * 8 + (t >> 5), kk = t & 31;
        if (n0 + nn < Nsub)
            D[(long)(d_nofs + n0 + nn) * d_ld + d_kofs + k0 + kk] = f2bf(tile[kk][nn]);
    }
}

// ================= G1: kv = x @ [Wk|Wv] + [bk|bv] (f32) =================
__global__ __launch_bounds__(256)
void gemm_kv_kernel(const float* __restrict__ x,
                    const float* __restrict__ Wk, const float* __restrict__ bk,
                    const float* __restrict__ Wv, const float* __restrict__ bv,
                    float* __restrict__ kvout)
{
    const int m0 = blockIdx.x * 64;
    const int n0 = blockIdx.y * 64;
    const int tid = threadIdx.x;
    const int tm = tid / 16, tn = tid % 16;
    constexpr int K = NIN, N = KVW;

    __shared__ __align__(16) float As[16][72];
    __shared__ __align__(16) float Ws[16][72];
    float acc[4][4] = {};

    for (int k0 = 0; k0 < K; k0 += 16) {
        {
            int kk = tid % 16, mb = (tid / 16) * 4;
            long col = k0 + kk;
            As[kk][mb+0] = x[(long)(m0+mb+0)*K + col];
            As[kk][mb+1] = x[(long)(m0+mb+1)*K + col];
            As[kk][mb+2] = x[(long)(m0+mb+2)*K + col];
            As[kk][mb+3] = x[(long)(m0+mb+3)*K + col];
        }
        {
            int c = tid % 64, kq = tid / 64;
            #pragma unroll
            for (int q = 0; q < 4; q++) {
                int kk = kq + q*4, cg = n0 + c;
                float v = 0;
                if (cg < IKS)    v = Wk[(long)(k0+kk)*IKS + cg];
                else if (cg < N) v = Wv[(long)(k0+kk)*IVS + (cg - IKS)];
                Ws[kk][c] = v;
            }
        }
        __syncthreads();
        #pragma unroll
        for (int kk = 0; kk < 16; kk++) {
            float4 a4 = *(const float4*)&As[kk][tm*4];
            float4 w4 = *(const float4*)&Ws[kk][tn*4];
            float av[4] = {a4.x,a4.y,a4.z,a4.w}, wv[4] = {w4.x,w4.y,w4.z,w4.w};
            #pragma unroll
            for (int i = 0; i < 4; i++)
                #pragma unroll
                for (int j = 0; j < 4; j++)
                    acc[i][j] = fmaf(av[i], wv[j], acc[i][j]);
        }
        __syncthreads();
    }
    #pragma unroll
    for (int i = 0; i < 4; i++) {
        int row = m0 + tm*4 + i;
        #pragma unroll
        for (int j = 0; j < 4; j++) {
            int cg = n0 + tn*4 + j;
            if (cg < N) {
                float bias = (cg < IKS) ? bk[cg] : bv[cg - IKS];
                kvout[(long)row*N + cg] = acc[i][j] + bias;
            }
        }
    }
}

// ================= G2: qry = hs @ Wq (f32, N=64 per u) =================
__global__ __launch_bounds__(256)
void gemm_qry_kernel(const float* __restrict__ A,
                     const float* __restrict__ W,
                     float* __restrict__ C)
{
    const int u  = blockIdx.z;
    const int m0 = blockIdx.x * 64;
    const int tid = threadIdx.x;
    const int tm = tid / 16, tn = tid % 16;
    constexpr int K = NH, N = IKS;
    const long lda = (long)NU * NH;

    __shared__ __align__(16) float As[16][72];
    __shared__ __align__(16) float Ws[16][72];
    const float* Au = A + (long)u * K;
    const float* Wu = W + (long)u * K * N;
    float acc[4][4] = {};

    for (int k0 = 0; k0 < K; k0 += 16) {
        {
            int kk = tid % 16, mb = (tid / 16) * 4;
            float v0=0,v1=0,v2=0,v3=0;
            if (k0 + kk < K) {
                long col = k0 + kk;
                v0 = Au[(long)(m0+mb+0)*lda + col];
                v1 = Au[(long)(m0+mb+1)*lda + col];
                v2 = Au[(long)(m0+mb+2)*lda + col];
                v3 = Au[(long)(m0+mb+3)*lda + col];
            }
            As[kk][mb+0]=v0; As[kk][mb+1]=v1; As[kk][mb+2]=v2; As[kk][mb+3]=v3;
        }
        {
            int c = tid % 64, kq = tid / 64;
            #pragma unroll
            for (int q = 0; q < 4; q++) {
                int kk = kq + q*4;
                float v = 0;
                if (k0 + kk < K && c < N) v = Wu[(long)(k0+kk)*N + c];
                Ws[kk][c] = v;
            }
        }
        __syncthreads();
        #pragma unroll
        for (int kk = 0; kk < 16; kk++) {
            float4 a4 = *(const float4*)&As[kk][tm*4];
            float4 w4 = *(const float4*)&Ws[kk][tn*4];
            float av[4] = {a4.x,a4.y,a4.z,a4.w}, wv[4] = {w4.x,w4.y,w4.z,w4.w};
            #pragma unroll
            for (int i = 0; i < 4; i++)
                #pragma unroll
                for (int j = 0; j < 4; j++)
                    acc[i][j] = fmaf(av[i], wv[j], acc[i][j]);
        }
        __syncthreads();
    }
    #pragma unroll
    for (int i = 0; i < 4; i++) {
        int row = m0 + tm*4 + i;
        #pragma unroll
        for (int j = 0; j < 4; j++) {
            int c = tn*4 + j;
            if (c < N)
                C[(long)row*(NU*IKS) + (long)u*IKS + c] = acc[i][j];
        }
    }
}

// ================= K3: scores / top-k mask =================
__global__ __launch_bounds__(64)
void score_kernel(const float* __restrict__ qry, const float* __restrict__ kv,
                  const float* __restrict__ bk,
                  float* __restrict__ c0, float* __restrict__ c1,
                  float* __restrict__ maskf)
{
    const int b = blockIdx.x;
    const int t = threadIdx.x;
    __shared__ float s0s[NU], s1s[NU];

    float k0v = kv[(long)b*KVW + t];
    float bkv = bk[t];
    for (int u = 0; u < NU; u++) {
        float q  = qry[((long)b*NU + u)*IKS + t];
        float p0 = q * k0v, p1 = q * bkv;
        #pragma unroll
        for (int off = 32; off > 0; off >>= 1) {
            p0 += __shfl_down(p0, off);
            p1 += __shfl_down(p1, off);
        }
        if (t == 0) { s0s[u] = p0 * 0.125f; s1s[u] = p1 * 0.125f; }
    }
    __syncthreads();
    if (t < NU) {
        int u = t;
        float su = s0s[u];
        int rank = 0;
        #pragma unroll
        for (int j = 0; j < NU; j++) {
            float sj = s0s[j];
            if (sj > su || (sj == su && j < u)) rank++;
        }
        float m = (rank < KTOP) ? 1.0f : 0.0f;
        float a = s0s[u], bb = s1s[u];
        float mx = fmaxf(a, bb);
        float e0 = expf(a - mx), e1 = expf(bb - mx);
        float p0 = e0 / (e0 + e1);
        c0[(long)b*NU + u]    = m * p0;
        c1[(long)b*NU + u]    = m * (1.0f - p0);
        maskf[(long)b*NU + u] = m;
    }
}

// ================= prep A for GRU GEMM (bf16, padded) =================
__global__ __launch_bounds__(256)
void prep_gruA_kernel(const float* __restrict__ kv, const float* __restrict__ bv,
                      const float* __restrict__ hs,
                      const float* __restrict__ c0, const float* __restrict__ c1,
                      u16* __restrict__ Ag)
{
    long id = (long)blockIdx.x * 256 + threadIdx.x;
    const long total = (long)NU * NB * (KGRU / 8);
    if (id >= total) return;
    int k8 = (int)(id % (KGRU / 8));
    int b  = (int)((id / (KGRU / 8)) % NB);
    int u  = (int)(id / ((long)(KGRU / 8) * NB));
    int k  = k8 * 8;
    u16 o[8];
    if (k < IVS) {
        float cv0 = c0[(long)b*NU + u], cv1 = c1[(long)b*NU + u];
        const float* kp = kv + (long)b*KVW + IKS + k;
        const float* bp = bv + k;
        #pragma unroll
        for (int i = 0; i < 8; i++) o[i] = f2bf(cv0*kp[i] + cv1*bp[i]);
    } else if (k >= HOFS && k < HOFS + NH) {
        const float* hp = hs + ((long)b*NU + u)*NH + (k - HOFS);
        #pragma unroll
        for (int i = 0; i < 8; i++) o[i] = f2bf(hp[i]);
    } else {
        #pragma unroll
        for (int i = 0; i < 8; i++) o[i] = 0;
    }
    *(short8*)&Ag[id * 8] = *(const short8*)o;
}

// ================= GRU MFMA GEMM (3 gates fused) =================
__global__ __launch_bounds__(256)
void gru_mfma_kernel(const u16* __restrict__ Ag, const u16* __restrict__ Wg,
                     const float* __restrict__ hs, u16* __restrict__ hnbf)
{
    const int u  = blockIdx.z;
    const int m0 = blockIdx.x * 128;
    const int n0 = blockIdx.y * 64;
    const int tid = threadIdx.x;
    const int wid = tid >> 6, lane = tid & 63;
    const int wm = wid >> 1, wn = wid & 1;
    const int lrow = lane & 15, lkq = lane >> 4;

    __shared__ __align__(16) u16 As[128 * 32];
    __shared__ __align__(16) u16 Bs[3 * 64 * 32];

    const u16* Au = Ag + (long)u * NB * KGRU;
    const u16* Wu = Wg + (long)u * 3 * NGATE * KGRU;

    f32x4 aR[4][2], aI[4][2], aNX[4][2], aNH[4][2];
    #pragma unroll
    for (int m = 0; m < 4; m++)
        #pragma unroll
        for (int n = 0; n < 2; n++) {
            aR[m][n] = (f32x4){0,0,0,0}; aI[m][n] = (f32x4){0,0,0,0};
            aNX[m][n] = (f32x4){0,0,0,0}; aNH[m][n] = (f32x4){0,0,0,0};
        }

    for (int ks = 0; ks < KGRU / 32; ++ks) {
        const int k0 = ks * 32;
        #pragma unroll
        for (int iss = 0; iss < 2; ++iss) {
            int row = (iss*256 + wid*64 + lane) >> 2;
            gl_lds16(Au + (long)(m0 + row)*KGRU + k0 + (lane & 3)*8,
                     &As[(iss*256 + wid*64) * 8]);
        }
        #pragma unroll
        for (int g = 0; g < 3; ++g) {
            int row = (wid*64 + lane) >> 2;
            gl_lds16(Wu + ((long)g*NGATE + n0 + row)*KGRU + k0 + (lane & 3)*8,
                     &Bs[(g*256 + wid*64) * 8]);
        }
        __syncthreads();

        short8 af[4], bR[2], bI[2], bN[2];
        #pragma unroll
        for (int m = 0; m < 4; m++)
            af[m] = *(const short8*)&As[(wm*64 + m*16 + lrow)*32 + lkq*8];
        #pragma unroll
        for (int n = 0; n < 2; n++) {
            int nr = wn*32 + n*16 + lrow;
            bR[n] = *(const short8*)&Bs[(0*64 + nr)*32 + lkq*8];
            bI[n] = *(const short8*)&Bs[(1*64 + nr)*32 + lkq*8];
            bN[n] = *(const short8*)&Bs[(2*64 + nr)*32 + lkq*8];
        }
        #pragma unroll
        for (int m = 0; m < 4; m++)
            #pragma unroll
            for (int n = 0; n < 2; n++) {
                aR[m][n] = __builtin_amdgcn_mfma_f32_16x16x32_bf16(af[m], bR[n], aR[m][n], 0, 0, 0);
                aI[m][n] = __builtin_amdgcn_mfma_f32_16x16x32_bf16(af[m], bI[n], aI[m][n], 0, 0, 0);
            }
        if (ks < HOFS / 32) {
            #pragma unroll
            for (int m = 0; m < 4; m++)
                #pragma unroll
                for (int n = 0; n < 2; n++)
                    aNX[m][n] = __builtin_amdgcn_mfma_f32_16x16x32_bf16(af[m], bN[n], aNX[m][n], 0, 0, 0);
        } else {
            #pragma unroll
            for (int m = 0; m < 4; m++)
                #pragma unroll
                for (int n = 0; n < 2; n++)
                    aNH[m][n] = __builtin_amdgcn_mfma_f32_16x16x32_bf16(af[m], bN[n], aNH[m][n], 0, 0, 0);
        }
        __syncthreads();
    }

    #pragma unroll
    for (int m = 0; m < 4; m++) {
        #pragma unroll
        for (int r = 0; r < 4; r++) {
            int row = m0 + wm*64 + m*16 + lkq*4 + r;   // b
            #pragma unroll
            for (int n = 0; n < 2; n++) {
                int col = n0 + wn*32 + n*16 + lrow;     // c in [0,640)
                u16 ov = 0;
                if (col < NH) {
                    float rg = 1.0f / (1.0f + expf(-aR[m][n][r]));
                    float ig = 1.0f / (1.0f + expf(-aI[m][n][r]));
                    float ng = tanhf(aNX[m][n][r] + rg * aNH[m][n][r]);
                    float h  = hs[((long)row*NU + u)*NH + col];
                    ov = f2bf(ng + ig * (h - ng));
                }
                hnbf[(long)u*NB*KH + (long)row*KH + col] = ov;
            }
        }
    }
}

// ================= generic 128x128 bf16 MFMA GEMM =================
// EPI=0: C[u*sCu + row*ldc + col] = acc   (all cols valid)
// EPI=1: final out with mask/hnew/h_old blend (guard col<NH), row local + bbase
template<int EPI>
__global__ __launch_bounds__(256)
void mfgemm_kernel(const u16* __restrict__ A, long sAu, int lda,
                   const u16* __restrict__ Bw, long sBu, int ldb,
                   float* __restrict__ C, long sCu, int ldc,
                   int ksteps,
                   const float* __restrict__ maskf,
                   const u16* __restrict__ hnbf,
                   const float* __restrict__ hs,
                   int bbase)
{
    const int u  = blockIdx.z;
    const int m0 = blockIdx.x * 128;
    const int n0 = blockIdx.y * 128;
    const int tid = threadIdx.x;
    const int wid = tid >> 6, lane = tid & 63;
    const int wm = wid >> 1, wn = wid & 1;
    const int lrow = lane & 15, lkq = lane >> 4;

    __shared__ __align__(16) u16 As[128 * 32];
    __shared__ __align__(16) u16 Bs[128 * 32];

    const u16* Au = A + (long)u * sAu;
    const u16* Bu = Bw + (long)u * sBu;

    f32x4 acc[4][4];
    #pragma unroll
    for (int m = 0; m < 4; m++)
        #pragma unroll
        for (int n = 0; n < 4; n++) acc[m][n] = (f32x4){0,0,0,0};

    for (int ks = 0; ks < ksteps; ++ks) {
        const int k0 = ks * 32;
        #pragma unroll
        for (int iss = 0; iss < 2; ++iss) {
            int row = (iss*256 + wid*64 + lane) >> 2;
            gl_lds16(Au + (long)(m0 + row)*lda + k0 + (lane & 3)*8,
                     &As[(iss*256 + wid*64) * 8]);
            int rowb = (iss*256 + wid*64 + lane) >> 2;
            gl_lds16(Bu + (long)(n0 + rowb)*ldb + k0 + (lane & 3)*8,
                     &Bs[(iss*256 + wid*64) * 8]);
        }
        __syncthreads();

        short8 af[4], bf[4];
        #pragma unroll
        for (int m = 0; m < 4; m++)
            af[m] = *(const short8*)&As[(wm*64 + m*16 + lrow)*32 + lkq*8];
        #pragma unroll
        for (int n = 0; n < 4; n++)
            bf[n] = *(const short8*)&Bs[(wn*64 + n*16 + lrow)*32 + lkq*8];
        #pragma unroll
        for (int m = 0; m < 4; m++)
            #pragma unroll
            for (int n = 0; n < 4; n++)
                acc[m][n] = __builtin_amdgcn_mfma_f32_16x16x32_bf16(af[m], bf[n], acc[m][n], 0, 0, 0);
        __syncthreads();
    }

    #pragma unroll
    for (int m = 0; m < 4; m++) {
        #pragma unroll
        for (int r = 0; r < 4; r++) {
            int row = m0 + wm*64 + m*16 + lkq*4 + r;
            #pragma unroll
            for (int n = 0; n < 4; n++) {
                int col = n0 + wn*64 + n*16 + lrow;
                float v = acc[m][n][r];
                if (EPI == 0) {
                    C[(long)u*sCu + (long)row*ldc + col] = v;
                } else {
                    if (col < NH) {
                        int b = bbase + row;
                        long o = ((long)b*NU + u)*NH + col;
                        float mk = maskf[(long)b*NU + u];
                        float hv = bf2f(hnbf[(long)u*NB*KH + (long)b*KH + col]);
                        C[o] = (mk > 0.5f) ? (v + hv) : hs[o];
                    }
                }
            }
        }
    }
}

// ================= K7: attention weights =================
__global__ __launch_bounds__(64)
void attw_kernel(const float* __restrict__ qk, const float* __restrict__ maskf,
                 float* __restrict__ attw)
{
    const int bh = blockIdx.x;
    const int b = bh / NCH, h = bh % NCH;
    const int t = threadIdx.x;
    __shared__ float lg[NU][NU];

    if (t < NU * NU) {
        int uq = t / NU, un = t % NU;
        const float* qp = qk + ((long)b*NU + uq)*QKW + h*32;
        const float* kp = qk + ((long)b*NU + un)*QKW + 128 + h*32;
        float s = 0;
        #pragma unroll
        for (int i = 0; i < 32; i++) s = fmaf(qp[i], kp[i], s);
        lg[uq][un] = s * 0.17677669529663687f;
    }
    __syncthreads();
    if (t < NU) {
        int uq = t;
        float mx = -1e30f;
        #pragma unroll
        for (int n = 0; n < NU; n++) mx = fmaxf(mx, lg[uq][n]);
        float e[NU], se = 0;
        #pragma unroll
        for (int n = 0; n < NU; n++) { e[n] = expf(lg[uq][n] - mx); se += e[n]; }
        float m = maskf[(long)b*NU + uq];
        float inv = m / se;
        #pragma unroll
        for (int n = 0; n < NU; n++)
            attw[(((long)b*NCH + h)*NU + uq)*NU + n] = e[n] * inv;
    }
}

// ================= ctx = att @ v -> bf16 =================
__global__ __launch_bounds__(256)
void ctx_kernel(const float* __restrict__ attw, const float* __restrict__ vbuf,
                u16* __restrict__ ctxbf, int bbase)
{
    long idx = (long)blockIdx.x * 256 + threadIdx.x;
    const long total = (long)BC * NU * VN;
    if (idx >= total) return;
    int c  = (int)(idx % VN);
    int uu = (int)((idx / VN) % NU);
    int bl = (int)(idx / ((long)VN * NU));
    float s = 0;
    if (c < VW) {
        int b = bbase + bl;
        int h = c / CVS;
        const float* aw = attw + (((long)b*NCH + h)*NU + uu)*NU;
        const float* vp = vbuf + (long)bl*NU*VN + c;
        #pragma unroll
        for (int n = 0; n < NU; n++) s = fmaf(aw[n], vp[(long)n*VN], s);
    }
    ctxbf[idx] = f2bf(s);
}

// ================= host launcher =================
extern "C" void kernel_launch(void* const* d_in, const int* in_sizes, int n_in,
                              void* d_out, int out_size, void* d_ws, size_t ws_size,
                              hipStream_t stream)
{
    const float* x    = (const float*)d_in[0];
    const float* hs   = (const float*)d_in[1];
    const float* Wk   = (const float*)d_in[2];
    const float* bk   = (const float*)d_in[3];
    const float* Wv   = (const float*)d_in[4];
    const float* bv   = (const float*)d_in[5];
    const float* Wq   = (const float*)d_in[6];
    const float* x2h  = (const float*)d_in[7];
    const float* h2h  = (const float*)d_in[8];
    const float* Wq_  = (const float*)d_in[9];
    const float* Wk_  = (const float*)d_in[10];
    const float* Wv_  = (const float*)d_in[11];
    const float* Wout = (const float*)d_in[12];
    float* out = (float*)d_out;
    float* ws  = (float*)d_ws;

    float* kv    = ws + OFF_KV;
    float* qry   = ws + OFF_QRY;
    float* c0b   = ws + OFF_C0;
    float* c1b   = ws + OFF_C1;
    float* maskf = ws + OFF_MASK;
    float* qk    = ws + OFF_QK;
    float* attw  = ws + OFF_ATTW;
    u16*   hnbf  = (u16*)(ws + OFF_HNBF);
    u16*   wqk   = (u16*)(ws + OFF_WQK);
    u16*   wv    = (u16*)(ws + OFF_WV);
    u16*   wout  = (u16*)(ws + OFF_WOUT);
    u16*   wgru  = (u16*)(ws + OFF_WGRU);
    u16*   agru  = (u16*)(ws + OFF_AGRU);
    float* vbuf  = ws + OFF_VBUF;
    u16*   ctxbf = (u16*)(ws + OFF_CTXB);

    // 0) zero-fill bf16 weight buffers (pads)
    zfill_kernel<<<2048, 256, 0, stream>>>((float4*)(ws + ZF_OFF), ZF_N4);

    // 1) weight conversions/transposes
    // qk: Wq_ -> rows 0..127, Wk_ -> rows 128..255; K=600 pad 640
    wtrans_kernel<<<dim3(19, 4, NU), 256, 0, stream>>>(
        Wq_, (long)NH*128, 128, 0, NH, 128, wqk, (long)QKW*KH, KH, 0, 0);
    wtrans_kernel<<<dim3(19, 4, NU), 256, 0, stream>>>(
        Wk_, (long)NH*128, 128, 0, NH, 128, wqk, (long)QKW*KH, KH, 128, 0);
    // v: Wv_ [600][2400] -> [2432][640]
    wtrans_kernel<<<dim3(19, 75, NU), 256, 0, stream>>>(
        Wv_, (long)NH*VW, VW, 0, NH, VW, wv, (long)VN*KH, KH, 0, 0);
    // out: Wout [2400][600] -> [640][2432]
    wtrans_kernel<<<dim3(76, 19, NU), 256, 0, stream>>>(
        Wout, (long)VW*NH, NH, 0, VW, NH, wout, (long)NGATE*VN, VN, 0, 0);
    // gru: x2h [400][1800] gate cols -> k 0..399; h2h [600][1800] -> k 416..1015
    for (int g = 0; g < 3; g++) {
        wtrans_kernel<<<dim3(13, 19, NU), 256, 0, stream>>>(
            x2h, (long)IVS*3*NH, 3*NH, g*NH, IVS, NH,
            wgru + (long)g*NGATE*KGRU, (long)3*NGATE*KGRU, KGRU, 0, 0);
        wtrans_kernel<<<dim3(19, 19, NU), 256, 0, stream>>>(
            h2h, (long)NH*3*NH, 3*NH, g*NH, NH, NH,
            wgru + (long)g*NGATE*KGRU, (long)3*NGATE*KGRU, KGRU, 0, HOFS);
    }

    // 2) f32 front-end
    gemm_kv_kernel<<<dim3(NB/64, (KVW+63)/64), 256, 0, stream>>>(x, Wk, bk, Wv, bv, kv);
    gemm_qry_kernel<<<dim3(NB/64, 1, NU), 256, 0, stream>>>(hs, Wq, qry);
    score_kernel<<<NB, 64, 0, stream>>>(qry, kv, bk, c0b, c1b, maskf);

    // 3) GRU A prep + GRU MFMA
    {
        long total = (long)NU * NB * (KGRU/8);
        prep_gruA_kernel<<<(unsigned)((total + 255)/256), 256, 0, stream>>>(
            kv, bv, hs, c0b, c1b, agru);
    }
    gru_mfma_kernel<<<dim3(NB/128, NGATE/64, NU), 256, 0, stream>>>(agru, wgru, hs, hnbf);

    // 4) qk projection (MFMA) + attention weights
    mfgemm_kernel<0><<<dim3(NB/128, QKW/128, NU), 256, 0, stream>>>(
        hnbf, (long)NB*KH, KH, wqk, (long)QKW*KH, KH,
        qk, (long)QKW, NU*QKW, KH/32, nullptr, nullptr, nullptr, 0);
    attw_kernel<<<NB*NCH, 64, 0, stream>>>(qk, maskf, attw);

    // 5) chunked v / ctx / out
    for (int ch = 0; ch < NCHUNK; ch++) {
        // v = hnew @ Wv_ : [BC][NU][2432] f32
        mfgemm_kernel<0><<<dim3(BC/128, VN/128, NU), 256, 0, stream>>>(
            hnbf + (long)ch*BC*KH, (long)NB*KH, KH, wv, (long)VN*KH, KH,
            vbuf, (long)VN, NU*VN, KH/32, nullptr, nullptr, nullptr, 0);
        // ctx = att @ v -> bf16
        {
            long tot = (long)BC * NU * VN;
            ctx_kernel<<<(unsigned)((tot + 255)/256), 256, 0, stream>>>(
                attw, vbuf, ctxbf, ch*BC);
        }
        // out = mask ? ctx@Wout + hnew : h_old
        mfgemm_kernel<1><<<dim3(BC/128, NGATE/128, NU), 256, 0, stream>>>(
            ctxbf, (long)VN, NU*VN, wout, (long)NGATE*VN, VN,
            out, 0, 0, VN/32, maskf, hnbf, hs, ch*BC);
    }
}

// Round 3
// 1473.637 us; speedup vs baseline: 5.5396x; 1.1775x over previous
//
#include <hip/hip_runtime.h>
#include <math.h>

typedef unsigned short u16;
typedef __attribute__((ext_vector_type(8))) short short8;
typedef __attribute__((ext_vector_type(4))) float f32x4;

// ---------------- problem constants ----------------
constexpr int NB   = 4096;   // B
constexpr int NU   = 6;      // U
constexpr int NIN  = 256;    // IN
constexpr int NH   = 600;    // H
constexpr int IKS  = 64;
constexpr int IVS  = 400;
constexpr int NCH  = 4;
constexpr int CVS  = 600;
constexpr int KTOP = 4;

constexpr int KVW  = IKS + IVS;      // 464
constexpr int QKW  = 256;            // q(128)|k(128)
constexpr int VW   = NCH * CVS;      // 2400

// padded MFMA dims
constexpr int KGRU = 1024;           // [inputs 0..399 |0| hs 416..1015 |0]
constexpr int HOFS = 416;            // hs starts here (13*32)
constexpr int NGATE = 640;           // 600 padded
constexpr int KH   = 640;            // hnew K padded
constexpr int VN   = 2432;           // 2400 padded (19*128)
constexpr int BC   = 512;
constexpr int NCHUNK = NB / BC;      // 8

// ---------------- ws layout (float offsets) ----------------
constexpr long OFF_KV   = 0;                                   // f32 [NB][464]
constexpr long OFF_QRY  = OFF_KV   + (long)NB * KVW;           // f32 [NB][NU][64]
constexpr long OFF_C0   = OFF_QRY  + (long)NB * NU * IKS;
constexpr long OFF_C1   = OFF_C0   + (long)NB * NU;
constexpr long OFF_MASK = OFF_C1   + (long)NB * NU;
constexpr long OFF_QK   = OFF_MASK + (long)NB * NU;            // f32 [NB][NU][256]
constexpr long OFF_ATTW = OFF_QK   + (long)NB * NU * QKW;      // f32 [NB][NCH][NU][NU]
constexpr long OFF_HNBF = OFF_ATTW + (long)NB * NCH * NU * NU; // bf16 [NU][NB][640]
constexpr long OFF_WQK  = OFF_HNBF + (long)NU * NB * KH / 2;   // bf16 [NU][256][640]
constexpr long OFF_WV   = OFF_WQK  + (long)NU * QKW * KH / 2;  // bf16 [NU][2432][640]
constexpr long OFF_WOUT = OFF_WV   + (long)NU * VN * KH / 2;   // bf16 [NU][640][2432]
constexpr long OFF_WGRU = OFF_WOUT + (long)NU * NGATE * VN / 2;// bf16 [NU][3][640][1024]
constexpr long OFF_AGRU = OFF_WGRU + (long)NU * 3 * NGATE * KGRU / 2; // bf16 [NU][NB][1024]
// aliased into AGRU region after GRU GEMM (chunk loop):
constexpr long OFF_VBUF = OFF_AGRU;                            // bf16 [BC][NU][2432]
constexpr long OFF_CTXB = OFF_VBUF + (long)BC * NU * VN / 2;   // bf16 [BC][NU][2432]
// zero-fill region: all bf16 weight buffers
constexpr long ZF_OFF = OFF_WQK;
constexpr long ZF_N4  = (OFF_AGRU - OFF_WQK) / 4;

// ---------------- helpers ----------------
__device__ __forceinline__ u16 f2bf(float f) {
    unsigned int x = __float_as_uint(f);
    x += 0x7FFFu + ((x >> 16) & 1u);
    return (u16)(x >> 16);
}
__device__ __forceinline__ float bf2f(u16 u) {
    return __uint_as_float(((unsigned int)u) << 16);
}
__device__ __forceinline__ void gl_lds16(const u16* g, u16* l) {
    __builtin_amdgcn_global_load_lds(
        (const __attribute__((address_space(1))) void*)g,
        (__attribute__((address_space(3))) void*)l, 16, 0, 0);
}

// ================= zero fill =================
__global__ __launch_bounds__(256)
void zfill_kernel(float4* __restrict__ p, long n4)
{
    long i = (long)blockIdx.x * 256 + threadIdx.x;
    long stride = (long)gridDim.x * 256;
    float4 z = {0.f, 0.f, 0.f, 0.f};
    for (; i < n4; i += stride) p[i] = z;
}

// ================= weight transpose f32[K][N] -> bf16[n][k] =================
__global__ __launch_bounds__(256)
void wtrans_kernel(const float* __restrict__ src, long s_u, int s_ld, int s_colofs,
                   int Ksrc, int Nsub,
                   u16* __restrict__ dst, long d_u, int d_ld, int d_nofs, int d_kofs)
{
    __shared__ float tile[32][33];
    const int u  = blockIdx.z;
    const int k0 = blockIdx.x * 32, n0 = blockIdx.y * 32;
    const int t  = threadIdx.x;
    const float* S = src + (long)u * s_u;
    u16* D = dst + (long)u * d_u;
    #pragma unroll
    for (int r = 0; r < 4; r++) {
        int kk = r * 8 + (t >> 5), nn = t & 31;
        float v = 0.f;
        if (k0 + kk < Ksrc && n0 + nn < Nsub)
            v = S[(long)(k0 + kk) * s_ld + s_colofs + n0 + nn];
        tile[kk][nn] = v;
    }
    __syncthreads();
    #pragma unroll
    for (int r = 0; r < 4; r++) {
        int nn = r * 8 + (t >> 5), kk = t & 31;
        if (n0 + nn < Nsub)
            D[(long)(d_nofs + n0 + nn) * d_ld + d_kofs + k0 + kk] = f2bf(tile[kk][nn]);
    }
}

// ================= G1: kv = x @ [Wk|Wv] + [bk|bv] (f32) =================
__global__ __launch_bounds__(256)
void gemm_kv_kernel(const float* __restrict__ x,
                    const float* __restrict__ Wk, const float* __restrict__ bk,
                    const float* __restrict__ Wv, const float* __restrict__ bv,
                    float* __restrict__ kvout)
{
    const int m0 = blockIdx.x * 64;
    const int n0 = blockIdx.y * 64;
    const int tid = threadIdx.x;
    const int tm = tid / 16, tn = tid % 16;
    constexpr int K = NIN, N = KVW;

    __shared__ __align__(16) float As[16][72];
    __shared__ __align__(16) float Ws[16][72];
    float acc[4][4] = {};

    for (int k0 = 0; k0 < K; k0 += 16) {
        {
            int kk = tid % 16, mb = (tid / 16) * 4;
            long col = k0 + kk;
            As[kk][mb+0] = x[(long)(m0+mb+0)*K + col];
            As[kk][mb+1] = x[(long)(m0+mb+1)*K + col];
            As[kk][mb+2] = x[(long)(m0+mb+2)*K + col];
            As[kk][mb+3] = x[(long)(m0+mb+3)*K + col];
        }
        {
            int c = tid % 64, kq = tid / 64;
            #pragma unroll
            for (int q = 0; q < 4; q++) {
                int kk = kq + q*4, cg = n0 + c;
                float v = 0;
                if (cg < IKS)    v = Wk[(long)(k0+kk)*IKS + cg];
                else if (cg < N) v = Wv[(long)(k0+kk)*IVS + (cg - IKS)];
                Ws[kk][c] = v;
            }
        }
        __syncthreads();
        #pragma unroll
        for (int kk = 0; kk < 16; kk++) {
            float4 a4 = *(const float4*)&As[kk][tm*4];
            float4 w4 = *(const float4*)&Ws[kk][tn*4];
            float av[4] = {a4.x,a4.y,a4.z,a4.w}, wv[4] = {w4.x,w4.y,w4.z,w4.w};
            #pragma unroll
            for (int i = 0; i < 4; i++)
                #pragma unroll
                for (int j = 0; j < 4; j++)
                    acc[i][j] = fmaf(av[i], wv[j], acc[i][j]);
        }
        __syncthreads();
    }
    #pragma unroll
    for (int i = 0; i < 4; i++) {
        int row = m0 + tm*4 + i;
        #pragma unroll
        for (int j = 0; j < 4; j++) {
            int cg = n0 + tn*4 + j;
            if (cg < N) {
                float bias = (cg < IKS) ? bk[cg] : bv[cg - IKS];
                kvout[(long)row*N + cg] = acc[i][j] + bias;
            }
        }
    }
}

// ================= G2: qry = hs @ Wq (f32, N=64 per u) =================
__global__ __launch_bounds__(256)
void gemm_qry_kernel(const float* __restrict__ A,
                     const float* __restrict__ W,
                     float* __restrict__ C)
{
    const int u  = blockIdx.z;
    const int m0 = blockIdx.x * 64;
    const int tid = threadIdx.x;
    const int tm = tid / 16, tn = tid % 16;
    constexpr int K = NH, N = IKS;
    const long lda = (long)NU * NH;

    __shared__ __align__(16) float As[16][72];
    __shared__ __align__(16) float Ws[16][72];
    const float* Au = A + (long)u * K;
    const float* Wu = W + (long)u * K * N;
    float acc[4][4] = {};

    for (int k0 = 0; k0 < K; k0 += 16) {
        {
            int kk = tid % 16, mb = (tid / 16) * 4;
            float v0=0,v1=0,v2=0,v3=0;
            if (k0 + kk < K) {
                long col = k0 + kk;
                v0 = Au[(long)(m0+mb+0)*lda + col];
                v1 = Au[(long)(m0+mb+1)*lda + col];
                v2 = Au[(long)(m0+mb+2)*lda + col];
                v3 = Au[(long)(m0+mb+3)*lda + col];
            }
            As[kk][mb+0]=v0; As[kk][mb+1]=v1; As[kk][mb+2]=v2; As[kk][mb+3]=v3;
        }
        {
            int c = tid % 64, kq = tid / 64;
            #pragma unroll
            for (int q = 0; q < 4; q++) {
                int kk = kq + q*4;
                float v = 0;
                if (k0 + kk < K && c < N) v = Wu[(long)(k0+kk)*N + c];
                Ws[kk][c] = v;
            }
        }
        __syncthreads();
        #pragma unroll
        for (int kk = 0; kk < 16; kk++) {
            float4 a4 = *(const float4*)&As[kk][tm*4];
            float4 w4 = *(const float4*)&Ws[kk][tn*4];
            float av[4] = {a4.x,a4.y,a4.z,a4.w}, wv[4] = {w4.x,w4.y,w4.z,w4.w};
            #pragma unroll
            for (int i = 0; i < 4; i++)
                #pragma unroll
                for (int j = 0; j < 4; j++)
                    acc[i][j] = fmaf(av[i], wv[j], acc[i][j]);
        }
        __syncthreads();
    }
    #pragma unroll
    for (int i = 0; i < 4; i++) {
        int row = m0 + tm*4 + i;
        #pragma unroll
        for (int j = 0; j < 4; j++) {
            int c = tn*4 + j;
            if (c < N)
                C[(long)row*(NU*IKS) + (long)u*IKS + c] = acc[i][j];
        }
    }
}

// ================= K3: scores / top-k mask =================
__global__ __launch_bounds__(64)
void score_kernel(const float* __restrict__ qry, const float* __restrict__ kv,
                  const float* __restrict__ bk,
                  float* __restrict__ c0, float* __restrict__ c1,
                  float* __restrict__ maskf)
{
    const int b = blockIdx.x;
    const int t = threadIdx.x;
    __shared__ float s0s[NU], s1s[NU];

    float k0v = kv[(long)b*KVW + t];
    float bkv = bk[t];
    for (int u = 0; u < NU; u++) {
        float q  = qry[((long)b*NU + u)*IKS + t];
        float p0 = q * k0v, p1 = q * bkv;
        #pragma unroll
        for (int off = 32; off > 0; off >>= 1) {
            p0 += __shfl_down(p0, off);
            p1 += __shfl_down(p1, off);
        }
        if (t == 0) { s0s[u] = p0 * 0.125f; s1s[u] = p1 * 0.125f; }
    }
    __syncthreads();
    if (t < NU) {
        int u = t;
        float su = s0s[u];
        int rank = 0;
        #pragma unroll
        for (int j = 0; j < NU; j++) {
            float sj = s0s[j];
            if (sj > su || (sj == su && j < u)) rank++;
        }
        float m = (rank < KTOP) ? 1.0f : 0.0f;
        float a = s0s[u], bb = s1s[u];
        float mx = fmaxf(a, bb);
        float e0 = expf(a - mx), e1 = expf(bb - mx);
        float p0 = e0 / (e0 + e1);
        c0[(long)b*NU + u]    = m * p0;
        c1[(long)b*NU + u]    = m * (1.0f - p0);
        maskf[(long)b*NU + u] = m;
    }
}

// ================= prep A for GRU GEMM (bf16, padded) =================
__global__ __launch_bounds__(256)
void prep_gruA_kernel(const float* __restrict__ kv, const float* __restrict__ bv,
                      const float* __restrict__ hs,
                      const float* __restrict__ c0, const float* __restrict__ c1,
                      u16* __restrict__ Ag)
{
    long id = (long)blockIdx.x * 256 + threadIdx.x;
    const long total = (long)NU * NB * (KGRU / 8);
    if (id >= total) return;
    int k8 = (int)(id % (KGRU / 8));
    int b  = (int)((id / (KGRU / 8)) % NB);
    int u  = (int)(id / ((long)(KGRU / 8) * NB));
    int k  = k8 * 8;
    u16 o[8];
    if (k < IVS) {
        float cv0 = c0[(long)b*NU + u], cv1 = c1[(long)b*NU + u];
        const float* kp = kv + (long)b*KVW + IKS + k;
        const float* bp = bv + k;
        #pragma unroll
        for (int i = 0; i < 8; i++) o[i] = f2bf(cv0*kp[i] + cv1*bp[i]);
    } else if (k >= HOFS && k < HOFS + NH) {
        const float* hp = hs + ((long)b*NU + u)*NH + (k - HOFS);
        #pragma unroll
        for (int i = 0; i < 8; i++) o[i] = f2bf(hp[i]);
    } else {
        #pragma unroll
        for (int i = 0; i < 8; i++) o[i] = 0;
    }
    *(short8*)&Ag[id * 8] = *(const short8*)o;
}

// ================= GRU MFMA GEMM (3 gates fused, 2-phase dbuf) =================
__global__ __launch_bounds__(256)
void gru_mfma_kernel(const u16* __restrict__ Ag, const u16* __restrict__ Wg,
                     const float* __restrict__ hs, u16* __restrict__ hnbf)
{
    const int u  = blockIdx.z;
    const int m0 = blockIdx.x * 128;
    const int n0 = blockIdx.y * 64;
    const int tid = threadIdx.x;
    const int wid = tid >> 6, lane = tid & 63;
    const int wm = wid >> 1, wn = wid & 1;
    const int lrow = lane & 15, lkq = lane >> 4;

    __shared__ __align__(16) u16 As[2][128 * 32];
    __shared__ __align__(16) u16 Bs[2][3 * 64 * 32];

    const u16* Au = Ag + (long)u * NB * KGRU;
    const u16* Wu = Wg + (long)u * 3 * NGATE * KGRU;

    f32x4 aR[4][2], aI[4][2], aNX[4][2], aNH[4][2];
    #pragma unroll
    for (int m = 0; m < 4; m++)
        #pragma unroll
        for (int n = 0; n < 2; n++) {
            aR[m][n] = (f32x4){0,0,0,0}; aI[m][n] = (f32x4){0,0,0,0};
            aNX[m][n] = (f32x4){0,0,0,0}; aNH[m][n] = (f32x4){0,0,0,0};
        }

    const int arow  = (wid*64 + lane) >> 2;      // shared by staging
    const int acol8 = (lane & 3) * 8;

#define GRU_STAGE(BUF, KS) do {                                              \
        const int k0s = (KS) * 32;                                           \
        gl_lds16(Au + (long)(m0 + arow)*KGRU + k0s + acol8,                  \
                 &As[BUF][(wid*64) * 8]);                                    \
        gl_lds16(Au + (long)(m0 + 64 + arow)*KGRU + k0s + acol8,             \
                 &As[BUF][(256 + wid*64) * 8]);                              \
        _Pragma("unroll")                                                    \
        for (int g = 0; g < 3; ++g)                                          \
            gl_lds16(Wu + ((long)g*NGATE + n0 + arow)*KGRU + k0s + acol8,    \
                     &Bs[BUF][(g*256 + wid*64) * 8]);                        \
    } while (0)

#define GRU_COMPUTE(BUF, KS) do {                                            \
        short8 af[4], bR[2], bI[2], bN[2];                                   \
        _Pragma("unroll")                                                    \
        for (int m = 0; m < 4; m++)                                          \
            af[m] = *(const short8*)&As[BUF][(wm*64 + m*16 + lrow)*32 + lkq*8]; \
        _Pragma("unroll")                                                    \
        for (int n = 0; n < 2; n++) {                                        \
            int nr = wn*32 + n*16 + lrow;                                    \
            bR[n] = *(const short8*)&Bs[BUF][(0*64 + nr)*32 + lkq*8];        \
            bI[n] = *(const short8*)&Bs[BUF][(1*64 + nr)*32 + lkq*8];        \
            bN[n] = *(const short8*)&Bs[BUF][(2*64 + nr)*32 + lkq*8];        \
        }                                                                    \
        _Pragma("unroll")                                                    \
        for (int m = 0; m < 4; m++)                                          \
            _Pragma("unroll")                                                \
            for (int n = 0; n < 2; n++) {                                    \
                aR[m][n] = __builtin_amdgcn_mfma_f32_16x16x32_bf16(af[m], bR[n], aR[m][n], 0, 0, 0); \
                aI[m][n] = __builtin_amdgcn_mfma_f32_16x16x32_bf16(af[m], bI[n], aI[m][n], 0, 0, 0); \
            }                                                                \
        if ((KS) < HOFS / 32) {                                              \
            _Pragma("unroll")                                                \
            for (int m = 0; m < 4; m++)                                      \
                _Pragma("unroll")                                            \
                for (int n = 0; n < 2; n++)                                  \
                    aNX[m][n] = __builtin_amdgcn_mfma_f32_16x16x32_bf16(af[m], bN[n], aNX[m][n], 0, 0, 0); \
        } else {                                                             \
            _Pragma("unroll")                                                \
            for (int m = 0; m < 4; m++)                                      \
                _Pragma("unroll")                                            \
                for (int n = 0; n < 2; n++)                                  \
                    aNH[m][n] = __builtin_amdgcn_mfma_f32_16x16x32_bf16(af[m], bN[n], aNH[m][n], 0, 0, 0); \
        }                                                                    \
    } while (0)

    constexpr int KSTEPS = KGRU / 32;   // 32 (even)
    GRU_STAGE(0, 0);
    __syncthreads();
    for (int ks = 0; ks < KSTEPS; ks += 2) {
        if (ks + 1 < KSTEPS) GRU_STAGE(1, ks + 1);
        GRU_COMPUTE(0, ks);
        __syncthreads();
        if (ks + 2 < KSTEPS) GRU_STAGE(0, ks + 2);
        GRU_COMPUTE(1, ks + 1);
        __syncthreads();
    }
#undef GRU_STAGE
#undef GRU_COMPUTE

    #pragma unroll
    for (int m = 0; m < 4; m++) {
        #pragma unroll
        for (int r = 0; r < 4; r++) {
            int row = m0 + wm*64 + m*16 + lkq*4 + r;   // b
            #pragma unroll
            for (int n = 0; n < 2; n++) {
                int col = n0 + wn*32 + n*16 + lrow;     // c in [0,640)
                u16 ov = 0;
                if (col < NH) {
                    float rg = 1.0f / (1.0f + expf(-aR[m][n][r]));
                    float ig = 1.0f / (1.0f + expf(-aI[m][n][r]));
                    float ng = tanhf(aNX[m][n][r] + rg * aNH[m][n][r]);
                    float h  = hs[((long)row*NU + u)*NH + col];
                    ov = f2bf(ng + ig * (h - ng));
                }
                hnbf[(long)u*NB*KH + (long)row*KH + col] = ov;
            }
        }
    }
}

// ================= generic 128x128 bf16 MFMA GEMM (2-phase dbuf) =================
// EPI=0: Cf[u*sCu + row*ldc + col] = acc (f32)
// EPI=1: final out with mask/hnew/h_old blend (guard col<NH)
// EPI=2: C16[u*sCu + row*ldc + col] = bf16(acc)
template<int EPI>
__global__ __launch_bounds__(256)
void mfgemm_kernel(const u16* __restrict__ A, long sAu, int lda,
                   const u16* __restrict__ Bw, long sBu, int ldb,
                   float* __restrict__ Cf, u16* __restrict__ C16,
                   long sCu, int ldc, int ksteps,
                   const float* __restrict__ maskf,
                   const u16* __restrict__ hnbf,
                   const float* __restrict__ hs,
                   int bbase)
{
    const int u  = blockIdx.z;
    const int m0 = blockIdx.x * 128;
    const int n0 = blockIdx.y * 128;
    const int tid = threadIdx.x;
    const int wid = tid >> 6, lane = tid & 63;
    const int wm = wid >> 1, wn = wid & 1;
    const int lrow = lane & 15, lkq = lane >> 4;

    __shared__ __align__(16) u16 As[2][128 * 32];
    __shared__ __align__(16) u16 Bs[2][128 * 32];

    const u16* Au = A + (long)u * sAu;
    const u16* Bu = Bw + (long)u * sBu;

    f32x4 acc[4][4];
    #pragma unroll
    for (int m = 0; m < 4; m++)
        #pragma unroll
        for (int n = 0; n < 4; n++) acc[m][n] = (f32x4){0,0,0,0};

    const int arow  = (wid*64 + lane) >> 2;
    const int acol8 = (lane & 3) * 8;

#define MF_STAGE(BUF, KS) do {                                               \
        const int k0s = (KS) * 32;                                           \
        gl_lds16(Au + (long)(m0 + arow)*lda + k0s + acol8,                   \
                 &As[BUF][(wid*64) * 8]);                                    \
        gl_lds16(Au + (long)(m0 + 64 + arow)*lda + k0s + acol8,              \
                 &As[BUF][(256 + wid*64) * 8]);                              \
        gl_lds16(Bu + (long)(n0 + arow)*ldb + k0s + acol8,                   \
                 &Bs[BUF][(wid*64) * 8]);                                    \
        gl_lds16(Bu + (long)(n0 + 64 + arow)*ldb + k0s + acol8,              \
                 &Bs[BUF][(256 + wid*64) * 8]);                              \
    } while (0)

#define MF_COMPUTE(BUF) do {                                                 \
        short8 af[4], bfr[4];                                                \
        _Pragma("unroll")                                                    \
        for (int m = 0; m < 4; m++)                                          \
            af[m] = *(const short8*)&As[BUF][(wm*64 + m*16 + lrow)*32 + lkq*8]; \
        _Pragma("unroll")                                                    \
        for (int n = 0; n < 4; n++)                                          \
            bfr[n] = *(const short8*)&Bs[BUF][(wn*64 + n*16 + lrow)*32 + lkq*8]; \
        _Pragma("unroll")                                                    \
        for (int m = 0; m < 4; m++)                                          \
            _Pragma("unroll")                                                \
            for (int n = 0; n < 4; n++)                                      \
                acc[m][n] = __builtin_amdgcn_mfma_f32_16x16x32_bf16(af[m], bfr[n], acc[m][n], 0, 0, 0); \
    } while (0)

    MF_STAGE(0, 0);
    __syncthreads();
    for (int ks = 0; ks < ksteps; ks += 2) {
        if (ks + 1 < ksteps) MF_STAGE(1, ks + 1);
        MF_COMPUTE(0);
        __syncthreads();
        if (ks + 2 < ksteps) MF_STAGE(0, ks + 2);
        MF_COMPUTE(1);
        __syncthreads();
    }
#undef MF_STAGE
#undef MF_COMPUTE

    #pragma unroll
    for (int m = 0; m < 4; m++) {
        #pragma unroll
        for (int r = 0; r < 4; r++) {
            int row = m0 + wm*64 + m*16 + lkq*4 + r;
            #pragma unroll
            for (int n = 0; n < 4; n++) {
                int col = n0 + wn*64 + n*16 + lrow;
                float v = acc[m][n][r];
                if (EPI == 0) {
                    Cf[(long)u*sCu + (long)row*ldc + col] = v;
                } else if (EPI == 2) {
                    C16[(long)u*sCu + (long)row*ldc + col] = f2bf(v);
                } else {
                    if (col < NH) {
                        int b = bbase + row;
                        long o = ((long)b*NU + u)*NH + col;
                        float mk = maskf[(long)b*NU + u];
                        float hv = bf2f(hnbf[(long)u*NB*KH + (long)b*KH + col]);
                        Cf[o] = (mk > 0.5f) ? (v + hv) : hs[o];
                    }
                }
            }
        }
    }
}

// ================= K7: attention weights =================
__global__ __launch_bounds__(64)
void attw_kernel(const float* __restrict__ qk, const float* __restrict__ maskf,
                 float* __restrict__ attw)
{
    const int bh = blockIdx.x;
    const int b = bh / NCH, h = bh % NCH;
    const int t = threadIdx.x;
    __shared__ float lg[NU][NU];

    if (t < NU * NU) {
        int uq = t / NU, un = t % NU;
        const float* qp = qk + ((long)b*NU + uq)*QKW + h*32;
        const float* kp = qk + ((long)b*NU + un)*QKW + 128 + h*32;
        float s = 0;
        #pragma unroll
        for (int i = 0; i < 32; i++) s = fmaf(qp[i], kp[i], s);
        lg[uq][un] = s * 0.17677669529663687f;
    }
    __syncthreads();
    if (t < NU) {
        int uq = t;
        float mx = -1e30f;
        #pragma unroll
        for (int n = 0; n < NU; n++) mx = fmaxf(mx, lg[uq][n]);
        float e[NU], se = 0;
        #pragma unroll
        for (int n = 0; n < NU; n++) { e[n] = expf(lg[uq][n] - mx); se += e[n]; }
        float m = maskf[(long)b*NU + uq];
        float inv = m / se;
        #pragma unroll
        for (int n = 0; n < NU; n++)
            attw[(((long)b*NCH + h)*NU + uq)*NU + n] = e[n] * inv;
    }
}

// ================= ctx = att @ v : each v read exactly once =================
// grid (VN/64, BC/32), block 256 = 32 b-rows x 8 c-chunks(8 wide)
__global__ __launch_bounds__(256)
void ctx2_kernel(const float* __restrict__ attw, const u16* __restrict__ v16,
                 u16* __restrict__ ctx16, int bbase)
{
    __shared__ float att_s[32][NCH * NU * NU];   // [bl][h*36+u*6+n] = 144
    const int c0 = blockIdx.x * 64;
    const int b0 = blockIdx.y * 32;
    const int tid = threadIdx.x;

    for (int i = tid; i < 32 * 144; i += 256) {
        int bl = i / 144, j = i % 144;
        att_s[bl][j] = attw[(long)(bbase + b0 + bl) * 144 + j];
    }
    __syncthreads();

    const int bl = tid >> 3;
    const int c  = c0 + (tid & 7) * 8;
    const long rowbase = (long)(b0 + bl) * NU;   // chunk-local

    if (c >= VW) {   // pad columns -> zero
        short8 z = {0,0,0,0,0,0,0,0};
        #pragma unroll
        for (int u = 0; u < NU; u++)
            *(short8*)&ctx16[(rowbase + u) * VN + c] = z;
        return;
    }
    const int h = c / CVS;
    const float* aw = &att_s[bl][h * 36];

    float acc[NU][8] = {};
    #pragma unroll
    for (int n = 0; n < NU; n++) {
        short8 vv = *(const short8*)&v16[(rowbase + n) * VN + c];
        float vf[8];
        #pragma unroll
        for (int i = 0; i < 8; i++) vf[i] = bf2f((u16)vv[i]);
        #pragma unroll
        for (int u = 0; u < NU; u++) {
            float a = aw[u * 6 + n];
            #pragma unroll
            for (int i = 0; i < 8; i++) acc[u][i] = fmaf(a, vf[i], acc[u][i]);
        }
    }
    #pragma unroll
    for (int u = 0; u < NU; u++) {
        short8 o;
        #pragma unroll
        for (int i = 0; i < 8; i++) o[i] = (short)f2bf(acc[u][i]);
        *(short8*)&ctx16[(rowbase + u) * VN + c] = o;
    }
}

// ================= host launcher =================
extern "C" void kernel_launch(void* const* d_in, const int* in_sizes, int n_in,
                              void* d_out, int out_size, void* d_ws, size_t ws_size,
                              hipStream_t stream)
{
    const float* x    = (const float*)d_in[0];
    const float* hs   = (const float*)d_in[1];
    const float* Wk   = (const float*)d_in[2];
    const float* bk   = (const float*)d_in[3];
    const float* Wv   = (const float*)d_in[4];
    const float* bv   = (const float*)d_in[5];
    const float* Wq   = (const float*)d_in[6];
    const float* x2h  = (const float*)d_in[7];
    const float* h2h  = (const float*)d_in[8];
    const float* Wq_  = (const float*)d_in[9];
    const float* Wk_  = (const float*)d_in[10];
    const float* Wv_  = (const float*)d_in[11];
    const float* Wout = (const float*)d_in[12];
    float* out = (float*)d_out;
    float* ws  = (float*)d_ws;

    float* kv    = ws + OFF_KV;
    float* qry   = ws + OFF_QRY;
    float* c0b   = ws + OFF_C0;
    float* c1b   = ws + OFF_C1;
    float* maskf = ws + OFF_MASK;
    float* qk    = ws + OFF_QK;
    float* attw  = ws + OFF_ATTW;
    u16*   hnbf  = (u16*)(ws + OFF_HNBF);
    u16*   wqk   = (u16*)(ws + OFF_WQK);
    u16*   wv    = (u16*)(ws + OFF_WV);
    u16*   wout  = (u16*)(ws + OFF_WOUT);
    u16*   wgru  = (u16*)(ws + OFF_WGRU);
    u16*   agru  = (u16*)(ws + OFF_AGRU);
    u16*   vbuf16 = (u16*)(ws + OFF_VBUF);
    u16*   ctx16  = (u16*)(ws + OFF_CTXB);

    // 0) zero-fill bf16 weight buffers (pads)
    zfill_kernel<<<2048, 256, 0, stream>>>((float4*)(ws + ZF_OFF), ZF_N4);

    // 1) weight conversions/transposes
    wtrans_kernel<<<dim3(19, 4, NU), 256, 0, stream>>>(
        Wq_, (long)NH*128, 128, 0, NH, 128, wqk, (long)QKW*KH, KH, 0, 0);
    wtrans_kernel<<<dim3(19, 4, NU), 256, 0, stream>>>(
        Wk_, (long)NH*128, 128, 0, NH, 128, wqk, (long)QKW*KH, KH, 128, 0);
    wtrans_kernel<<<dim3(19, 75, NU), 256, 0, stream>>>(
        Wv_, (long)NH*VW, VW, 0, NH, VW, wv, (long)VN*KH, KH, 0, 0);
    wtrans_kernel<<<dim3(76, 19, NU), 256, 0, stream>>>(
        Wout, (long)VW*NH, NH, 0, VW, NH, wout, (long)NGATE*VN, VN, 0, 0);
    for (int g = 0; g < 3; g++) {
        wtrans_kernel<<<dim3(13, 19, NU), 256, 0, stream>>>(
            x2h, (long)IVS*3*NH, 3*NH, g*NH, IVS, NH,
            wgru + (long)g*NGATE*KGRU, (long)3*NGATE*KGRU, KGRU, 0, 0);
        wtrans_kernel<<<dim3(19, 19, NU), 256, 0, stream>>>(
            h2h, (long)NH*3*NH, 3*NH, g*NH, NH, NH,
            wgru + (long)g*NGATE*KGRU, (long)3*NGATE*KGRU, KGRU, 0, HOFS);
    }

    // 2) f32 front-end
    gemm_kv_kernel<<<dim3(NB/64, (KVW+63)/64), 256, 0, stream>>>(x, Wk, bk, Wv, bv, kv);
    gemm_qry_kernel<<<dim3(NB/64, 1, NU), 256, 0, stream>>>(hs, Wq, qry);
    score_kernel<<<NB, 64, 0, stream>>>(qry, kv, bk, c0b, c1b, maskf);

    // 3) GRU A prep + GRU MFMA
    {
        long total = (long)NU * NB * (KGRU/8);
        prep_gruA_kernel<<<(unsigned)((total + 255)/256), 256, 0, stream>>>(
            kv, bv, hs, c0b, c1b, agru);
    }
    gru_mfma_kernel<<<dim3(NB/128, NGATE/64, NU), 256, 0, stream>>>(agru, wgru, hs, hnbf);

    // 4) qk projection (MFMA) + attention weights
    mfgemm_kernel<0><<<dim3(NB/128, QKW/128, NU), 256, 0, stream>>>(
        hnbf, (long)NB*KH, KH, wqk, (long)QKW*KH, KH,
        qk, nullptr, (long)QKW, NU*QKW, KH/32, nullptr, nullptr, nullptr, 0);
    attw_kernel<<<NB*NCH, 64, 0, stream>>>(qk, maskf, attw);

    // 5) chunked v / ctx / out
    for (int ch = 0; ch < NCHUNK; ch++) {
        // v = hnew @ Wv_ -> bf16 [BC][NU][VN]
        mfgemm_kernel<2><<<dim3(BC/128, VN/128, NU), 256, 0, stream>>>(
            hnbf + (long)ch*BC*KH, (long)NB*KH, KH, wv, (long)VN*KH, KH,
            nullptr, vbuf16, (long)VN, NU*VN, KH/32, nullptr, nullptr, nullptr, 0);
        // ctx = att @ v (each v read once) -> bf16
        ctx2_kernel<<<dim3(VN/64, BC/32), 256, 0, stream>>>(
            attw, vbuf16, ctx16, ch*BC);
        // out = mask ? ctx@Wout + hnew : h_old
        mfgemm_kernel<1><<<dim3(BC/128, NGATE/128, NU), 256, 0, stream>>>(
            ctx16, (long)VN, NU*VN, wout, (long)NGATE*VN, VN,
            out, nullptr, 0, 0, VN/32, maskf, hnbf, hs, ch*BC);
    }
}

// Round 4
// 1043.042 us; speedup vs baseline: 7.8264x; 1.4128x over previous
//
#include <hip/hip_runtime.h>
#include <math.h>

typedef unsigned short u16;
typedef __attribute__((ext_vector_type(8))) short short8;
typedef __attribute__((ext_vector_type(4))) float f32x4;

// ---------------- problem constants ----------------
constexpr int NB   = 4096;   // B
constexpr int NU   = 6;      // U
constexpr int NIN  = 256;    // IN
constexpr int NH   = 600;    // H
constexpr int IKS  = 64;
constexpr int IVS  = 400;
constexpr int NCH  = 4;
constexpr int CVS  = 600;
constexpr int KTOP = 4;

constexpr int KVW  = IKS + IVS;      // 464
constexpr int QKW  = 256;            // q(128)|k(128)
constexpr int VW   = NCH * CVS;      // 2400

// padded MFMA dims
constexpr int KGRU = 1024;           // [inputs 0..399 |0| hs 416..1015 |0]
constexpr int HOFS = 416;            // hs starts here (13*32)
constexpr int NGATE = 640;           // 600 padded
constexpr int KH   = 640;            // hnew K padded
constexpr int VN   = 2432;           // 2400 padded (19*128)
constexpr int BC   = 1024;
constexpr int NCHUNK = NB / BC;      // 4

// ---------------- ws layout (float offsets) ----------------
constexpr long OFF_KV   = 0;                                   // f32 [NB][464]
constexpr long OFF_QRY  = OFF_KV   + (long)NB * KVW;           // f32 [NB][NU][64]
constexpr long OFF_C0   = OFF_QRY  + (long)NB * NU * IKS;
constexpr long OFF_C1   = OFF_C0   + (long)NB * NU;
constexpr long OFF_MASK = OFF_C1   + (long)NB * NU;
constexpr long OFF_QK   = OFF_MASK + (long)NB * NU;            // f32 [NB][NU][256]
constexpr long OFF_ATTW = OFF_QK   + (long)NB * NU * QKW;      // f32 [NB][NCH][NU][NU]
constexpr long OFF_HNBF = OFF_ATTW + (long)NB * NCH * NU * NU; // bf16 [NU][NB][640]
constexpr long OFF_WQK  = OFF_HNBF + (long)NU * NB * KH / 2;   // bf16 [NU][256][640]
constexpr long OFF_WV   = OFF_WQK  + (long)NU * QKW * KH / 2;  // bf16 [NU][2432][640]
constexpr long OFF_WOUT = OFF_WV   + (long)NU * VN * KH / 2;   // bf16 [NU][640][2432]
constexpr long OFF_WGRU = OFF_WOUT + (long)NU * NGATE * VN / 2;// bf16 [NU][3][640][1024]
constexpr long OFF_AGRU = OFF_WGRU + (long)NU * 3 * NGATE * KGRU / 2; // bf16 [NU][NB][1024]
// aliased onto WGRU+AGRU after GRU GEMM (both dead by then):
constexpr long OFF_VBUF = OFF_WGRU;                            // bf16 [BC][NU][2432]
constexpr long OFF_CTXB = OFF_VBUF + (long)BC * NU * VN / 2;   // bf16 [BC][NU][2432]
// zero-fill region: all bf16 weight buffers
constexpr long ZF_OFF = OFF_WQK;
constexpr long ZF_N4  = (OFF_AGRU - OFF_WQK) / 4;

// ---------------- helpers ----------------
__device__ __forceinline__ u16 f2bf(float f) {
    unsigned int x = __float_as_uint(f);
    x += 0x7FFFu + ((x >> 16) & 1u);
    return (u16)(x >> 16);
}
__device__ __forceinline__ float bf2f(u16 u) {
    return __uint_as_float(((unsigned int)u) << 16);
}
__device__ __forceinline__ void gl_lds16(const u16* g, u16* l) {
    __builtin_amdgcn_global_load_lds(
        (const __attribute__((address_space(1))) void*)g,
        (__attribute__((address_space(3))) void*)l, 16, 0, 0);
}

// counted-wait / barrier primitives (T3+T4-lite; never drain vmcnt to 0 mid-loop)
#define WAITVM_(N) asm volatile("s_waitcnt vmcnt(" #N ")" ::: "memory")
#define WAITVM(N)  WAITVM_(N)
#define WAITLG()   asm volatile("s_waitcnt lgkmcnt(0)" ::: "memory")
#define SBAR()     do { __builtin_amdgcn_sched_barrier(0); \
                        __builtin_amdgcn_s_barrier();      \
                        __builtin_amdgcn_sched_barrier(0); } while (0)

// ================= zero fill =================
__global__ __launch_bounds__(256)
void zfill_kernel(float4* __restrict__ p, long n4)
{
    long i = (long)blockIdx.x * 256 + threadIdx.x;
    long stride = (long)gridDim.x * 256;
    float4 z = {0.f, 0.f, 0.f, 0.f};
    for (; i < n4; i += stride) p[i] = z;
}

// ================= weight transpose f32[K][N] -> bf16[n][k] =================
__global__ __launch_bounds__(256)
void wtrans_kernel(const float* __restrict__ src, long s_u, int s_ld, int s_colofs,
                   int Ksrc, int Nsub,
                   u16* __restrict__ dst, long d_u, int d_ld, int d_nofs, int d_kofs)
{
    __shared__ float tile[32][33];
    const int u  = blockIdx.z;
    const int k0 = blockIdx.x * 32, n0 = blockIdx.y * 32;
    const int t  = threadIdx.x;
    const float* S = src + (long)u * s_u;
    u16* D = dst + (long)u * d_u;
    #pragma unroll
    for (int r = 0; r < 4; r++) {
        int kk = r * 8 + (t >> 5), nn = t & 31;
        float v = 0.f;
        if (k0 + kk < Ksrc && n0 + nn < Nsub)
            v = S[(long)(k0 + kk) * s_ld + s_colofs + n0 + nn];
        tile[kk][nn] = v;
    }
    __syncthreads();
    #pragma unroll
    for (int r = 0; r < 4; r++) {
        int nn = r * 8 + (t >> 5), kk = t & 31;
        if (n0 + nn < Nsub)
            D[(long)(d_nofs + n0 + nn) * d_ld + d_kofs + k0 + kk] = f2bf(tile[kk][nn]);
    }
}

// ================= G1: kv = x @ [Wk|Wv] + [bk|bv] (f32) =================
__global__ __launch_bounds__(256)
void gemm_kv_kernel(const float* __restrict__ x,
                    const float* __restrict__ Wk, const float* __restrict__ bk,
                    const float* __restrict__ Wv, const float* __restrict__ bv,
                    float* __restrict__ kvout)
{
    const int m0 = blockIdx.x * 64;
    const int n0 = blockIdx.y * 64;
    const int tid = threadIdx.x;
    const int tm = tid / 16, tn = tid % 16;
    constexpr int K = NIN, N = KVW;

    __shared__ __align__(16) float As[16][72];
    __shared__ __align__(16) float Ws[16][72];
    float acc[4][4] = {};

    for (int k0 = 0; k0 < K; k0 += 16) {
        {
            int kk = tid % 16, mb = (tid / 16) * 4;
            long col = k0 + kk;
            As[kk][mb+0] = x[(long)(m0+mb+0)*K + col];
            As[kk][mb+1] = x[(long)(m0+mb+1)*K + col];
            As[kk][mb+2] = x[(long)(m0+mb+2)*K + col];
            As[kk][mb+3] = x[(long)(m0+mb+3)*K + col];
        }
        {
            int c = tid % 64, kq = tid / 64;
            #pragma unroll
            for (int q = 0; q < 4; q++) {
                int kk = kq + q*4, cg = n0 + c;
                float v = 0;
                if (cg < IKS)    v = Wk[(long)(k0+kk)*IKS + cg];
                else if (cg < N) v = Wv[(long)(k0+kk)*IVS + (cg - IKS)];
                Ws[kk][c] = v;
            }
        }
        __syncthreads();
        #pragma unroll
        for (int kk = 0; kk < 16; kk++) {
            float4 a4 = *(const float4*)&As[kk][tm*4];
            float4 w4 = *(const float4*)&Ws[kk][tn*4];
            float av[4] = {a4.x,a4.y,a4.z,a4.w}, wv[4] = {w4.x,w4.y,w4.z,w4.w};
            #pragma unroll
            for (int i = 0; i < 4; i++)
                #pragma unroll
                for (int j = 0; j < 4; j++)
                    acc[i][j] = fmaf(av[i], wv[j], acc[i][j]);
        }
        __syncthreads();
    }
    #pragma unroll
    for (int i = 0; i < 4; i++) {
        int row = m0 + tm*4 + i;
        #pragma unroll
        for (int j = 0; j < 4; j++) {
            int cg = n0 + tn*4 + j;
            if (cg < N) {
                float bias = (cg < IKS) ? bk[cg] : bv[cg - IKS];
                kvout[(long)row*N + cg] = acc[i][j] + bias;
            }
        }
    }
}

// ================= G2: qry = hs @ Wq (f32, N=64 per u) =================
__global__ __launch_bounds__(256)
void gemm_qry_kernel(const float* __restrict__ A,
                     const float* __restrict__ W,
                     float* __restrict__ C)
{
    const int u  = blockIdx.z;
    const int m0 = blockIdx.x * 64;
    const int tid = threadIdx.x;
    const int tm = tid / 16, tn = tid % 16;
    constexpr int K = NH, N = IKS;
    const long lda = (long)NU * NH;

    __shared__ __align__(16) float As[16][72];
    __shared__ __align__(16) float Ws[16][72];
    const float* Au = A + (long)u * K;
    const float* Wu = W + (long)u * K * N;
    float acc[4][4] = {};

    for (int k0 = 0; k0 < K; k0 += 16) {
        {
            int kk = tid % 16, mb = (tid / 16) * 4;
            float v0=0,v1=0,v2=0,v3=0;
            if (k0 + kk < K) {
                long col = k0 + kk;
                v0 = Au[(long)(m0+mb+0)*lda + col];
                v1 = Au[(long)(m0+mb+1)*lda + col];
                v2 = Au[(long)(m0+mb+2)*lda + col];
                v3 = Au[(long)(m0+mb+3)*lda + col];
            }
            As[kk][mb+0]=v0; As[kk][mb+1]=v1; As[kk][mb+2]=v2; As[kk][mb+3]=v3;
        }
        {
            int c = tid % 64, kq = tid / 64;
            #pragma unroll
            for (int q = 0; q < 4; q++) {
                int kk = kq + q*4;
                float v = 0;
                if (k0 + kk < K && c < N) v = Wu[(long)(k0+kk)*N + c];
                Ws[kk][c] = v;
            }
        }
        __syncthreads();
        #pragma unroll
        for (int kk = 0; kk < 16; kk++) {
            float4 a4 = *(const float4*)&As[kk][tm*4];
            float4 w4 = *(const float4*)&Ws[kk][tn*4];
            float av[4] = {a4.x,a4.y,a4.z,a4.w}, wv[4] = {w4.x,w4.y,w4.z,w4.w};
            #pragma unroll
            for (int i = 0; i < 4; i++)
                #pragma unroll
                for (int j = 0; j < 4; j++)
                    acc[i][j] = fmaf(av[i], wv[j], acc[i][j]);
        }
        __syncthreads();
    }
    #pragma unroll
    for (int i = 0; i < 4; i++) {
        int row = m0 + tm*4 + i;
        #pragma unroll
        for (int j = 0; j < 4; j++) {
            int c = tn*4 + j;
            if (c < N)
                C[(long)row*(NU*IKS) + (long)u*IKS + c] = acc[i][j];
        }
    }
}

// ================= K3: scores / top-k mask =================
__global__ __launch_bounds__(64)
void score_kernel(const float* __restrict__ qry, const float* __restrict__ kv,
                  const float* __restrict__ bk,
                  float* __restrict__ c0, float* __restrict__ c1,
                  float* __restrict__ maskf)
{
    const int b = blockIdx.x;
    const int t = threadIdx.x;
    __shared__ float s0s[NU], s1s[NU];

    float k0v = kv[(long)b*KVW + t];
    float bkv = bk[t];
    for (int u = 0; u < NU; u++) {
        float q  = qry[((long)b*NU + u)*IKS + t];
        float p0 = q * k0v, p1 = q * bkv;
        #pragma unroll
        for (int off = 32; off > 0; off >>= 1) {
            p0 += __shfl_down(p0, off);
            p1 += __shfl_down(p1, off);
        }
        if (t == 0) { s0s[u] = p0 * 0.125f; s1s[u] = p1 * 0.125f; }
    }
    __syncthreads();
    if (t < NU) {
        int u = t;
        float su = s0s[u];
        int rank = 0;
        #pragma unroll
        for (int j = 0; j < NU; j++) {
            float sj = s0s[j];
            if (sj > su || (sj == su && j < u)) rank++;
        }
        float m = (rank < KTOP) ? 1.0f : 0.0f;
        float a = s0s[u], bb = s1s[u];
        float mx = fmaxf(a, bb);
        float e0 = expf(a - mx), e1 = expf(bb - mx);
        float p0 = e0 / (e0 + e1);
        c0[(long)b*NU + u]    = m * p0;
        c1[(long)b*NU + u]    = m * (1.0f - p0);
        maskf[(long)b*NU + u] = m;
    }
}

// ================= prep A for GRU GEMM (bf16, padded) =================
__global__ __launch_bounds__(256)
void prep_gruA_kernel(const float* __restrict__ kv, const float* __restrict__ bv,
                      const float* __restrict__ hs,
                      const float* __restrict__ c0, const float* __restrict__ c1,
                      u16* __restrict__ Ag)
{
    long id = (long)blockIdx.x * 256 + threadIdx.x;
    const long total = (long)NU * NB * (KGRU / 8);
    if (id >= total) return;
    int k8 = (int)(id % (KGRU / 8));
    int b  = (int)((id / (KGRU / 8)) % NB);
    int u  = (int)(id / ((long)(KGRU / 8) * NB));
    int k  = k8 * 8;
    u16 o[8];
    if (k < IVS) {
        float cv0 = c0[(long)b*NU + u], cv1 = c1[(long)b*NU + u];
        const float* kp = kv + (long)b*KVW + IKS + k;
        const float* bp = bv + k;
        #pragma unroll
        for (int i = 0; i < 8; i++) o[i] = f2bf(cv0*kp[i] + cv1*bp[i]);
    } else if (k >= HOFS && k < HOFS + NH) {
        const float* hp = hs + ((long)b*NU + u)*NH + (k - HOFS);
        #pragma unroll
        for (int i = 0; i < 8; i++) o[i] = f2bf(hp[i]);
    } else {
        #pragma unroll
        for (int i = 0; i < 8; i++) o[i] = 0;
    }
    *(short8*)&Ag[id * 8] = *(const short8*)o;
}

// ================= GRU MFMA (3 gates fused; BK=64 phases, 3-buf counted) ====
// LDS tiles: As 128x64 u16 (128B rows), Bs 192x64. XOR-swizzle chunk^(row&7).
__global__ __launch_bounds__(256)
void gru_mfma_kernel(const u16* __restrict__ Ag, const u16* __restrict__ Wg,
                     const float* __restrict__ hs, u16* __restrict__ hnbf)
{
    const int u  = blockIdx.z;
    const int m0 = blockIdx.x * 128;
    const int n0 = blockIdx.y * 64;
    const int tid = threadIdx.x;
    const int wid = tid >> 6, lane = tid & 63;
    const int wm = wid >> 1, wn = wid & 1;
    const int lrow = lane & 15, lkq = lane >> 4;
    const int l8 = lane & 7, lr8 = lane >> 3;
    const int rsw = lrow & 7;                 // read-side XOR key

    __shared__ __align__(16) u16 As[3][128 * 64];
    __shared__ __align__(16) u16 Bs[3][192 * 64];

    const u16* Au = Ag + (long)u * NB * KGRU;
    const u16* Wu = Wg + (long)u * 3 * NGATE * KGRU;

    f32x4 aR[4][2], aI[4][2], aNX[4][2], aNH[4][2];
    #pragma unroll
    for (int m = 0; m < 4; m++)
        #pragma unroll
        for (int n = 0; n < 2; n++) {
            aR[m][n] = (f32x4){0,0,0,0}; aI[m][n] = (f32x4){0,0,0,0};
            aNX[m][n] = (f32x4){0,0,0,0}; aNH[m][n] = (f32x4){0,0,0,0};
        }

// stage one BK=64 phase: 4 A-calls + 6 B-calls = 10 gl_lds (NST=10)
#define GSTAGE(BUF, PH_) do {                                                 \
        const long kk0 = (long)(PH_) * 64;                                    \
        _Pragma("unroll")                                                     \
        for (int i2 = 0; i2 < 4; i2++) {                                      \
            int rw = i2*32 + wid*8 + lr8;                                     \
            gl_lds16(Au + (long)(m0 + rw)*KGRU + kk0 + ((l8 ^ (rw & 7)) * 8), \
                     &As[BUF][(i2*32 + wid*8) * 64]);                         \
        }                                                                     \
        _Pragma("unroll")                                                     \
        for (int j2 = 0; j2 < 6; j2++) {                                      \
            int r = j2*32 + wid*8 + lr8;                                      \
            int g = r >> 6, rn = r & 63;                                      \
            gl_lds16(Wu + ((long)g*NGATE + n0 + rn)*KGRU + kk0                \
                        + ((l8 ^ (r & 7)) * 8),                               \
                     &Bs[BUF][(j2*32 + wid*8) * 64]);                         \
        }                                                                     \
    } while (0)

#define GCOMPUTE(BUF, PH_) do {                                               \
        _Pragma("unroll")                                                     \
        for (int ks2 = 0; ks2 < 2; ks2++) {                                   \
            const int cofs = (((ks2*4 + lkq) ^ rsw) * 8);                     \
            short8 af[4], bR[2], bI[2], bN[2];                                \
            _Pragma("unroll")                                                 \
            for (int m = 0; m < 4; m++)                                       \
                af[m] = *(const short8*)&As[BUF][(wm*64 + m*16 + lrow)*64 + cofs]; \
            _Pragma("unroll")                                                 \
            for (int n = 0; n < 2; n++) {                                     \
                int nr = wn*32 + n*16 + lrow;                                 \
                bR[n] = *(const short8*)&Bs[BUF][(0*64 + nr)*64 + cofs];      \
                bI[n] = *(const short8*)&Bs[BUF][(1*64 + nr)*64 + cofs];      \
                bN[n] = *(const short8*)&Bs[BUF][(2*64 + nr)*64 + cofs];      \
            }                                                                 \
            _Pragma("unroll")                                                 \
            for (int m = 0; m < 4; m++)                                       \
                _Pragma("unroll")                                             \
                for (int n = 0; n < 2; n++) {                                 \
                    aR[m][n] = __builtin_amdgcn_mfma_f32_16x16x32_bf16(af[m], bR[n], aR[m][n], 0, 0, 0); \
                    aI[m][n] = __builtin_amdgcn_mfma_f32_16x16x32_bf16(af[m], bI[n], aI[m][n], 0, 0, 0); \
                }                                                             \
            if (2*(PH_) + ks2 < HOFS/32) {                                    \
                _Pragma("unroll")                                             \
                for (int m = 0; m < 4; m++)                                   \
                    _Pragma("unroll")                                         \
                    for (int n = 0; n < 2; n++)                               \
                        aNX[m][n] = __builtin_amdgcn_mfma_f32_16x16x32_bf16(af[m], bN[n], aNX[m][n], 0, 0, 0); \
            } else {                                                          \
                _Pragma("unroll")                                             \
                for (int m = 0; m < 4; m++)                                   \
                    _Pragma("unroll")                                         \
                    for (int n = 0; n < 2; n++)                               \
                        aNH[m][n] = __builtin_amdgcn_mfma_f32_16x16x32_bf16(af[m], bN[n], aNH[m][n], 0, 0, 0); \
            }                                                                 \
        }                                                                     \
    } while (0)

// phase: stage T+2 into (B+2)%3; wait own older stages; barrier; compute; drain lgkm; barrier
#define GPH(B, T, W) do {                                                     \
        if ((T) + 2 < 16) GSTAGE(((B)+2)%3, (T)+2);                           \
        WAITVM(W); SBAR();                                                    \
        GCOMPUTE(B, T);                                                       \
        WAITLG(); SBAR();                                                     \
    } while (0)

    GSTAGE(0, 0);
    GSTAGE(1, 1);
    for (int t = 0; t < 12; t += 3) { GPH(0, t, 20); GPH(1, t+1, 20); GPH(2, t+2, 20); }
    GPH(0, 12, 20); GPH(1, 13, 20); GPH(2, 14, 10); GPH(0, 15, 0);
#undef GPH
#undef GCOMPUTE
#undef GSTAGE

    #pragma unroll
    for (int m = 0; m < 4; m++) {
        #pragma unroll
        for (int r = 0; r < 4; r++) {
            int row = m0 + wm*64 + m*16 + lkq*4 + r;   // b
            #pragma unroll
            for (int n = 0; n < 2; n++) {
                int col = n0 + wn*32 + n*16 + lrow;     // c in [0,640)
                u16 ov = 0;
                if (col < NH) {
                    float rg = 1.0f / (1.0f + expf(-aR[m][n][r]));
                    float ig = 1.0f / (1.0f + expf(-aI[m][n][r]));
                    float ng = tanhf(aNX[m][n][r] + rg * aNH[m][n][r]);
                    float h  = hs[((long)row*NU + u)*NH + col];
                    ov = f2bf(ng + ig * (h - ng));
                }
                hnbf[(long)u*NB*KH + (long)row*KH + col] = ov;
            }
        }
    }
}

// ================= generic 128x128 bf16 MFMA GEMM (3-buf counted) =========
// EPI=0: f32 store; EPI=1: final out blend; EPI=2: bf16 store
template<int EPI>
__global__ __launch_bounds__(256, 2)
void mfgemm_kernel(const u16* __restrict__ A, long sAu, int lda,
                   const u16* __restrict__ Bw, long sBu, int ldb,
                   float* __restrict__ Cf, u16* __restrict__ C16,
                   long sCu, int ldc, int ksteps,
                   const float* __restrict__ maskf,
                   const u16* __restrict__ hnbf,
                   const float* __restrict__ hs,
                   int bbase)
{
    const int u  = blockIdx.z;
    const int m0 = blockIdx.x * 128;
    const int n0 = blockIdx.y * 128;
    const int tid = threadIdx.x;
    const int wid = tid >> 6, lane = tid & 63;
    const int wm = wid >> 1, wn = wid & 1;
    const int lrow = lane & 15, lkq = lane >> 4;
    const int l4 = lane & 3, lr4 = lane >> 2;
    const int rsw = (lrow >> 1) & 3;           // read-side XOR key (64B rows)

    __shared__ __align__(16) u16 As[3][128 * 32];
    __shared__ __align__(16) u16 Bs[3][128 * 32];

    const u16* Au = A + (long)u * sAu;
    const u16* Bu = Bw + (long)u * sBu;

    f32x4 acc[4][4];
    #pragma unroll
    for (int m = 0; m < 4; m++)
        #pragma unroll
        for (int n = 0; n < 4; n++) acc[m][n] = (f32x4){0,0,0,0};

// stage one BK=32 step: 2 A + 2 B calls = 4 gl_lds (NST=4)
#define MSTAGE(BUF, KS) do {                                                  \
        const long kk0 = (long)(KS) * 32;                                     \
        _Pragma("unroll")                                                     \
        for (int i2 = 0; i2 < 2; i2++) {                                      \
            int rw = i2*64 + wid*16 + lr4;                                    \
            int co = ((l4 ^ ((rw >> 1) & 3)) * 8);                            \
            gl_lds16(Au + (long)(m0 + rw)*lda + kk0 + co,                     \
                     &As[BUF][(i2*64 + wid*16) * 32]);                        \
            gl_lds16(Bu + (long)(n0 + rw)*ldb + kk0 + co,                     \
                     &Bs[BUF][(i2*64 + wid*16) * 32]);                        \
        }                                                                     \
    } while (0)

#define MCOMPUTE(BUF) do {                                                    \
        const int cofs = ((lkq ^ rsw) * 8);                                   \
        short8 af[4], bfr[4];                                                 \
        _Pragma("unroll")                                                     \
        for (int m = 0; m < 4; m++)                                           \
            af[m] = *(const short8*)&As[BUF][(wm*64 + m*16 + lrow)*32 + cofs];\
        _Pragma("unroll")                                                     \
        for (int n = 0; n < 4; n++)                                           \
            bfr[n] = *(const short8*)&Bs[BUF][(wn*64 + n*16 + lrow)*32 + cofs];\
        _Pragma("unroll")                                                     \
        for (int m = 0; m < 4; m++)                                           \
            _Pragma("unroll")                                                 \
            for (int n = 0; n < 4; n++)                                       \
                acc[m][n] = __builtin_amdgcn_mfma_f32_16x16x32_bf16(af[m], bfr[n], acc[m][n], 0, 0, 0); \
    } while (0)

#define MPH(B, T, W) do {                                                     \
        if ((T) + 2 < ksteps) MSTAGE(((B)+2)%3, (T)+2);                       \
        WAITVM(W); SBAR();                                                    \
        MCOMPUTE(B);                                                          \
        WAITLG(); SBAR();                                                     \
    } while (0)

    MSTAGE(0, 0);
    MSTAGE(1, 1);
    int t = 0;
    for (; t + 3 <= ksteps - 2; t += 3) { MPH(0, t, 8); MPH(1, t+1, 8); MPH(2, t+2, 8); }
    {
        int r = ksteps - t;
        if (r == 4)      { MPH(0, t, 8); MPH(1, t+1, 8); MPH(2, t+2, 4); MPH(0, t+3, 0); }
        else if (r == 3) { MPH(0, t, 8); MPH(1, t+1, 4); MPH(2, t+2, 0); }
        else             { MPH(0, t, 4); MPH(1, t+1, 0); }
    }
#undef MPH
#undef MCOMPUTE
#undef MSTAGE

    #pragma unroll
    for (int m = 0; m < 4; m++) {
        #pragma unroll
        for (int r = 0; r < 4; r++) {
            int row = m0 + wm*64 + m*16 + lkq*4 + r;
            #pragma unroll
            for (int n = 0; n < 4; n++) {
                int col = n0 + wn*64 + n*16 + lrow;
                float v = acc[m][n][r];
                if (EPI == 0) {
                    Cf[(long)u*sCu + (long)row*ldc + col] = v;
                } else if (EPI == 2) {
                    C16[(long)u*sCu + (long)row*ldc + col] = f2bf(v);
                } else {
                    if (col < NH) {
                        int b = bbase + row;
                        long o = ((long)b*NU + u)*NH + col;
                        float mk = maskf[(long)b*NU + u];
                        float hv = bf2f(hnbf[(long)u*NB*KH + (long)b*KH + col]);
                        Cf[o] = (mk > 0.5f) ? (v + hv) : hs[o];
                    }
                }
            }
        }
    }
}

// ================= K7: attention weights =================
__global__ __launch_bounds__(64)
void attw_kernel(const float* __restrict__ qk, const float* __restrict__ maskf,
                 float* __restrict__ attw)
{
    const int bh = blockIdx.x;
    const int b = bh / NCH, h = bh % NCH;
    const int t = threadIdx.x;
    __shared__ float lg[NU][NU];

    if (t < NU * NU) {
        int uq = t / NU, un = t % NU;
        const float* qp = qk + ((long)b*NU + uq)*QKW + h*32;
        const float* kp = qk + ((long)b*NU + un)*QKW + 128 + h*32;
        float s = 0;
        #pragma unroll
        for (int i = 0; i < 32; i++) s = fmaf(qp[i], kp[i], s);
        lg[uq][un] = s * 0.17677669529663687f;
    }
    __syncthreads();
    if (t < NU) {
        int uq = t;
        float mx = -1e30f;
        #pragma unroll
        for (int n = 0; n < NU; n++) mx = fmaxf(mx, lg[uq][n]);
        float e[NU], se = 0;
        #pragma unroll
        for (int n = 0; n < NU; n++) { e[n] = expf(lg[uq][n] - mx); se += e[n]; }
        float m = maskf[(long)b*NU + uq];
        float inv = m / se;
        #pragma unroll
        for (int n = 0; n < NU; n++)
            attw[(((long)b*NCH + h)*NU + uq)*NU + n] = e[n] * inv;
    }
}

// ================= ctx = att @ v : each v read exactly once =================
// grid (VN/64, BC/32), block 256 = 32 b-rows x 8 c-chunks(8 wide)
__global__ __launch_bounds__(256)
void ctx2_kernel(const float* __restrict__ attw, const u16* __restrict__ v16,
                 u16* __restrict__ ctx16, int bbase)
{
    __shared__ float att_s[32][NCH * NU * NU];   // [bl][h*36+u*6+n] = 144
    const int c0 = blockIdx.x * 64;
    const int b0 = blockIdx.y * 32;
    const int tid = threadIdx.x;

    for (int i = tid; i < 32 * 144; i += 256) {
        int bl = i / 144, j = i % 144;
        att_s[bl][j] = attw[(long)(bbase + b0 + bl) * 144 + j];
    }
    __syncthreads();

    const int bl = tid >> 3;
    const int c  = c0 + (tid & 7) * 8;
    const long rowbase = (long)(b0 + bl) * NU;   // chunk-local

    if (c >= VW) {   // pad columns -> zero
        short8 z = {0,0,0,0,0,0,0,0};
        #pragma unroll
        for (int u = 0; u < NU; u++)
            *(short8*)&ctx16[(rowbase + u) * VN + c] = z;
        return;
    }
    const int h = c / CVS;
    const float* aw = &att_s[bl][h * 36];

    float acc[NU][8] = {};
    #pragma unroll
    for (int n = 0; n < NU; n++) {
        short8 vv = *(const short8*)&v16[(rowbase + n) * VN + c];
        float vf[8];
        #pragma unroll
        for (int i = 0; i < 8; i++) vf[i] = bf2f((u16)vv[i]);
        #pragma unroll
        for (int u = 0; u < NU; u++) {
            float a = aw[u * 6 + n];
            #pragma unroll
            for (int i = 0; i < 8; i++) acc[u][i] = fmaf(a, vf[i], acc[u][i]);
        }
    }
    #pragma unroll
    for (int u = 0; u < NU; u++) {
        short8 o;
        #pragma unroll
        for (int i = 0; i < 8; i++) o[i] = (short)f2bf(acc[u][i]);
        *(short8*)&ctx16[(rowbase + u) * VN + c] = o;
    }
}

// ================= host launcher =================
extern "C" void kernel_launch(void* const* d_in, const int* in_sizes, int n_in,
                              void* d_out, int out_size, void* d_ws, size_t ws_size,
                              hipStream_t stream)
{
    const float* x    = (const float*)d_in[0];
    const float* hs   = (const float*)d_in[1];
    const float* Wk   = (const float*)d_in[2];
    const float* bk   = (const float*)d_in[3];
    const float* Wv   = (const float*)d_in[4];
    const float* bv   = (const float*)d_in[5];
    const float* Wq   = (const float*)d_in[6];
    const float* x2h  = (const float*)d_in[7];
    const float* h2h  = (const float*)d_in[8];
    const float* Wq_  = (const float*)d_in[9];
    const float* Wk_  = (const float*)d_in[10];
    const float* Wv_  = (const float*)d_in[11];
    const float* Wout = (const float*)d_in[12];
    float* out = (float*)d_out;
    float* ws  = (float*)d_ws;

    float* kv    = ws + OFF_KV;
    float* qry   = ws + OFF_QRY;
    float* c0b   = ws + OFF_C0;
    float* c1b   = ws + OFF_C1;
    float* maskf = ws + OFF_MASK;
    float* qk    = ws + OFF_QK;
    float* attw  = ws + OFF_ATTW;
    u16*   hnbf  = (u16*)(ws + OFF_HNBF);
    u16*   wqk   = (u16*)(ws + OFF_WQK);
    u16*   wv    = (u16*)(ws + OFF_WV);
    u16*   wout  = (u16*)(ws + OFF_WOUT);
    u16*   wgru  = (u16*)(ws + OFF_WGRU);
    u16*   agru  = (u16*)(ws + OFF_AGRU);
    u16*   vbuf16 = (u16*)(ws + OFF_VBUF);
    u16*   ctx16  = (u16*)(ws + OFF_CTXB);

    // 0) zero-fill bf16 weight buffers (pads)
    zfill_kernel<<<2048, 256, 0, stream>>>((float4*)(ws + ZF_OFF), ZF_N4);

    // 1) weight conversions/transposes
    wtrans_kernel<<<dim3(19, 4, NU), 256, 0, stream>>>(
        Wq_, (long)NH*128, 128, 0, NH, 128, wqk, (long)QKW*KH, KH, 0, 0);
    wtrans_kernel<<<dim3(19, 4, NU), 256, 0, stream>>>(
        Wk_, (long)NH*128, 128, 0, NH, 128, wqk, (long)QKW*KH, KH, 128, 0);
    wtrans_kernel<<<dim3(19, 75, NU), 256, 0, stream>>>(
        Wv_, (long)NH*VW, VW, 0, NH, VW, wv, (long)VN*KH, KH, 0, 0);
    wtrans_kernel<<<dim3(76, 19, NU), 256, 0, stream>>>(
        Wout, (long)VW*NH, NH, 0, VW, NH, wout, (long)NGATE*VN, VN, 0, 0);
    for (int g = 0; g < 3; g++) {
        wtrans_kernel<<<dim3(13, 19, NU), 256, 0, stream>>>(
            x2h, (long)IVS*3*NH, 3*NH, g*NH, IVS, NH,
            wgru + (long)g*NGATE*KGRU, (long)3*NGATE*KGRU, KGRU, 0, 0);
        wtrans_kernel<<<dim3(19, 19, NU), 256, 0, stream>>>(
            h2h, (long)NH*3*NH, 3*NH, g*NH, NH, NH,
            wgru + (long)g*NGATE*KGRU, (long)3*NGATE*KGRU, KGRU, 0, HOFS);
    }

    // 2) f32 front-end
    gemm_kv_kernel<<<dim3(NB/64, (KVW+63)/64), 256, 0, stream>>>(x, Wk, bk, Wv, bv, kv);
    gemm_qry_kernel<<<dim3(NB/64, 1, NU), 256, 0, stream>>>(hs, Wq, qry);
    score_kernel<<<NB, 64, 0, stream>>>(qry, kv, bk, c0b, c1b, maskf);

    // 3) GRU A prep + GRU MFMA
    {
        long total = (long)NU * NB * (KGRU/8);
        prep_gruA_kernel<<<(unsigned)((total + 255)/256), 256, 0, stream>>>(
            kv, bv, hs, c0b, c1b, agru);
    }
    gru_mfma_kernel<<<dim3(NB/128, NGATE/64, NU), 256, 0, stream>>>(agru, wgru, hs, hnbf);

    // 4) qk projection (MFMA) + attention weights
    mfgemm_kernel<0><<<dim3(NB/128, QKW/128, NU), 256, 0, stream>>>(
        hnbf, (long)NB*KH, KH, wqk, (long)QKW*KH, KH,
        qk, nullptr, (long)QKW, NU*QKW, KH/32, nullptr, nullptr, nullptr, 0);
    attw_kernel<<<NB*NCH, 64, 0, stream>>>(qk, maskf, attw);

    // 5) chunked v / ctx / out  (BC=1024, 4 chunks)
    for (int ch = 0; ch < NCHUNK; ch++) {
        // v = hnew @ Wv_ -> bf16 [BC][NU][VN]
        mfgemm_kernel<2><<<dim3(BC/128, VN/128, NU), 256, 0, stream>>>(
            hnbf + (long)ch*BC*KH, (long)NB*KH, KH, wv, (long)VN*KH, KH,
            nullptr, vbuf16, (long)VN, NU*VN, KH/32, nullptr, nullptr, nullptr, 0);
        // ctx = att @ v (each v read once) -> bf16
        ctx2_kernel<<<dim3(VN/64, BC/32), 256, 0, stream>>>(
            attw, vbuf16, ctx16, ch*BC);
        // out = mask ? ctx@Wout + hnew : h_old
        mfgemm_kernel<1><<<dim3(BC/128, NGATE/128, NU), 256, 0, stream>>>(
            ctx16, (long)VN, NU*VN, wout, (long)NGATE*VN, VN,
            out, nullptr, 0, 0, VN/32, maskf, hnbf, hs, ch*BC);
    }
}

// Round 5
// 931.829 us; speedup vs baseline: 8.7605x; 1.1193x over previous
//
#include <hip/hip_runtime.h>
#include <math.h>

typedef unsigned short u16;
typedef __attribute__((ext_vector_type(8))) short short8;
typedef __attribute__((ext_vector_type(4))) float f32x4;

// ---------------- problem constants ----------------
constexpr int NB   = 4096;   // B
constexpr int NU   = 6;      // U
constexpr int NIN  = 256;    // IN
constexpr int NH   = 600;    // H
constexpr int IKS  = 64;
constexpr int IVS  = 400;
constexpr int NCH  = 4;
constexpr int CVS  = 600;
constexpr int KTOP = 4;

constexpr int KVW  = IKS + IVS;      // 464
constexpr int QKW  = 256;            // q(128)|k(128)
constexpr int VW   = NCH * CVS;      // 2400

// padded MFMA dims
constexpr int KGRU = 1024;           // [inputs 0..399 |0| hs 416..1015 |0]
constexpr int HOFS = 416;            // hs starts here (13*32)
constexpr int NGATE = 640;           // 600 padded
constexpr int KH   = 640;            // hnew K padded
constexpr int VN   = 2432;           // 2400 padded (19*128)
constexpr int BC   = 1024;
constexpr int NCHUNK = NB / BC;      // 4

// ---------------- ws layout (float offsets) ----------------
constexpr long OFF_KV   = 0;                                   // f32 [NB][464]
constexpr long OFF_QRY  = OFF_KV   + (long)NB * KVW;           // f32 [NB][NU][64]
constexpr long OFF_C0   = OFF_QRY  + (long)NB * NU * IKS;
constexpr long OFF_C1   = OFF_C0   + (long)NB * NU;
constexpr long OFF_MASK = OFF_C1   + (long)NB * NU;
constexpr long OFF_QK   = OFF_MASK + (long)NB * NU;            // f32 [NB][NU][256]
constexpr long OFF_ATTW = OFF_QK   + (long)NB * NU * QKW;      // f32 [NB][NCH][NU][NU]
constexpr long OFF_HNBF = OFF_ATTW + (long)NB * NCH * NU * NU; // bf16 [NU][NB][640]
constexpr long OFF_WQK  = OFF_HNBF + (long)NU * NB * KH / 2;   // bf16 [NU][256][640]
constexpr long OFF_WV   = OFF_WQK  + (long)NU * QKW * KH / 2;  // bf16 [NU][2432][640]
constexpr long OFF_WOUT = OFF_WV   + (long)NU * VN * KH / 2;   // bf16 [NU][640][2432]
constexpr long OFF_WGRU = OFF_WOUT + (long)NU * NGATE * VN / 2;// bf16 [NU][3][640][1024]
constexpr long OFF_AGRU = OFF_WGRU + (long)NU * 3 * NGATE * KGRU / 2; // bf16 [NU][NB][1024]
// aliased onto WGRU+AGRU after GRU GEMM (both dead by then):
constexpr long OFF_VBUF = OFF_WGRU;                            // bf16 [BC][NU][2432]
constexpr long OFF_CTXB = OFF_VBUF + (long)BC * NU * VN / 2;   // bf16 [BC][NU][2432]

// ---------------- helpers ----------------
__device__ __forceinline__ u16 f2bf(float f) {
    unsigned int x = __float_as_uint(f);
    x += 0x7FFFu + ((x >> 16) & 1u);
    return (u16)(x >> 16);
}
__device__ __forceinline__ float bf2f(u16 u) {
    return __uint_as_float(((unsigned int)u) << 16);
}
__device__ __forceinline__ void gl_lds16(const u16* g, u16* l) {
    __builtin_amdgcn_global_load_lds(
        (const __attribute__((address_space(1))) void*)g,
        (__attribute__((address_space(3))) void*)l, 16, 0, 0);
}

// counted-wait / barrier primitives (never drain vmcnt to 0 mid-loop)
#define WAITVM_(N) asm volatile("s_waitcnt vmcnt(" #N ")" ::: "memory")
#define WAITVM(N)  WAITVM_(N)
#define WAITLG()   asm volatile("s_waitcnt lgkmcnt(0)" ::: "memory")
#define SBAR()     do { __builtin_amdgcn_sched_barrier(0); \
                        __builtin_amdgcn_s_barrier();      \
                        __builtin_amdgcn_sched_barrier(0); } while (0)

// ================= weight transpose f32[K][N] -> bf16[n][k] =================
// note: k-pads (k >= Ksrc up to tile edge) ARE written (zeros); n-pads are not
// (all n-pad consumers are epilogue-guarded).
__global__ __launch_bounds__(256)
void wtrans_kernel(const float* __restrict__ src, long s_u, int s_ld, int s_colofs,
                   int Ksrc, int Nsub,
                   u16* __restrict__ dst, long d_u, int d_ld, int d_nofs, int d_kofs)
{
    __shared__ float tile[32][33];
    const int u  = blockIdx.z;
    const int k0 = blockIdx.x * 32, n0 = blockIdx.y * 32;
    const int t  = threadIdx.x;
    const float* S = src + (long)u * s_u;
    u16* D = dst + (long)u * d_u;
    #pragma unroll
    for (int r = 0; r < 4; r++) {
        int kk = r * 8 + (t >> 5), nn = t & 31;
        float v = 0.f;
        if (k0 + kk < Ksrc && n0 + nn < Nsub)
            v = S[(long)(k0 + kk) * s_ld + s_colofs + n0 + nn];
        tile[kk][nn] = v;
    }
    __syncthreads();
    #pragma unroll
    for (int r = 0; r < 4; r++) {
        int nn = r * 8 + (t >> 5), kk = t & 31;
        if (n0 + nn < Nsub)
            D[(long)(d_nofs + n0 + nn) * d_ld + d_kofs + k0 + kk] = f2bf(tile[kk][nn]);
    }
}

// ================= G1: kv = x @ [Wk|Wv] + [bk|bv] (f32) =================
__global__ __launch_bounds__(256)
void gemm_kv_kernel(const float* __restrict__ x,
                    const float* __restrict__ Wk, const float* __restrict__ bk,
                    const float* __restrict__ Wv, const float* __restrict__ bv,
                    float* __restrict__ kvout)
{
    const int m0 = blockIdx.x * 64;
    const int n0 = blockIdx.y * 64;
    const int tid = threadIdx.x;
    const int tm = tid / 16, tn = tid % 16;
    constexpr int K = NIN, N = KVW;

    __shared__ __align__(16) float As[16][72];
    __shared__ __align__(16) float Ws[16][72];
    float acc[4][4] = {};

    for (int k0 = 0; k0 < K; k0 += 16) {
        {
            int kk = tid % 16, mb = (tid / 16) * 4;
            long col = k0 + kk;
            As[kk][mb+0] = x[(long)(m0+mb+0)*K + col];
            As[kk][mb+1] = x[(long)(m0+mb+1)*K + col];
            As[kk][mb+2] = x[(long)(m0+mb+2)*K + col];
            As[kk][mb+3] = x[(long)(m0+mb+3)*K + col];
        }
        {
            int c = tid % 64, kq = tid / 64;
            #pragma unroll
            for (int q = 0; q < 4; q++) {
                int kk = kq + q*4, cg = n0 + c;
                float v = 0;
                if (cg < IKS)    v = Wk[(long)(k0+kk)*IKS + cg];
                else if (cg < N) v = Wv[(long)(k0+kk)*IVS + (cg - IKS)];
                Ws[kk][c] = v;
            }
        }
        __syncthreads();
        #pragma unroll
        for (int kk = 0; kk < 16; kk++) {
            float4 a4 = *(const float4*)&As[kk][tm*4];
            float4 w4 = *(const float4*)&Ws[kk][tn*4];
            float av[4] = {a4.x,a4.y,a4.z,a4.w}, wv[4] = {w4.x,w4.y,w4.z,w4.w};
            #pragma unroll
            for (int i = 0; i < 4; i++)
                #pragma unroll
                for (int j = 0; j < 4; j++)
                    acc[i][j] = fmaf(av[i], wv[j], acc[i][j]);
        }
        __syncthreads();
    }
    #pragma unroll
    for (int i = 0; i < 4; i++) {
        int row = m0 + tm*4 + i;
        #pragma unroll
        for (int j = 0; j < 4; j++) {
            int cg = n0 + tn*4 + j;
            if (cg < N) {
                float bias = (cg < IKS) ? bk[cg] : bv[cg - IKS];
                kvout[(long)row*N + cg] = acc[i][j] + bias;
            }
        }
    }
}

// ================= G2: qry = hs @ Wq (f32, N=64 per u) =================
__global__ __launch_bounds__(256)
void gemm_qry_kernel(const float* __restrict__ A,
                     const float* __restrict__ W,
                     float* __restrict__ C)
{
    const int u  = blockIdx.z;
    const int m0 = blockIdx.x * 64;
    const int tid = threadIdx.x;
    const int tm = tid / 16, tn = tid % 16;
    constexpr int K = NH, N = IKS;
    const long lda = (long)NU * NH;

    __shared__ __align__(16) float As[16][72];
    __shared__ __align__(16) float Ws[16][72];
    const float* Au = A + (long)u * K;
    const float* Wu = W + (long)u * K * N;
    float acc[4][4] = {};

    for (int k0 = 0; k0 < K; k0 += 16) {
        {
            int kk = tid % 16, mb = (tid / 16) * 4;
            float v0=0,v1=0,v2=0,v3=0;
            if (k0 + kk < K) {
                long col = k0 + kk;
                v0 = Au[(long)(m0+mb+0)*lda + col];
                v1 = Au[(long)(m0+mb+1)*lda + col];
                v2 = Au[(long)(m0+mb+2)*lda + col];
                v3 = Au[(long)(m0+mb+3)*lda + col];
            }
            As[kk][mb+0]=v0; As[kk][mb+1]=v1; As[kk][mb+2]=v2; As[kk][mb+3]=v3;
        }
        {
            int c = tid % 64, kq = tid / 64;
            #pragma unroll
            for (int q = 0; q < 4; q++) {
                int kk = kq + q*4;
                float v = 0;
                if (k0 + kk < K && c < N) v = Wu[(long)(k0+kk)*N + c];
                Ws[kk][c] = v;
            }
        }
        __syncthreads();
        #pragma unroll
        for (int kk = 0; kk < 16; kk++) {
            float4 a4 = *(const float4*)&As[kk][tm*4];
            float4 w4 = *(const float4*)&Ws[kk][tn*4];
            float av[4] = {a4.x,a4.y,a4.z,a4.w}, wv[4] = {w4.x,w4.y,w4.z,w4.w};
            #pragma unroll
            for (int i = 0; i < 4; i++)
                #pragma unroll
                for (int j = 0; j < 4; j++)
                    acc[i][j] = fmaf(av[i], wv[j], acc[i][j]);
        }
        __syncthreads();
    }
    #pragma unroll
    for (int i = 0; i < 4; i++) {
        int row = m0 + tm*4 + i;
        #pragma unroll
        for (int j = 0; j < 4; j++) {
            int c = tn*4 + j;
            if (c < N)
                C[(long)row*(NU*IKS) + (long)u*IKS + c] = acc[i][j];
        }
    }
}

// ================= K3: scores / top-k mask =================
__global__ __launch_bounds__(64)
void score_kernel(const float* __restrict__ qry, const float* __restrict__ kv,
                  const float* __restrict__ bk,
                  float* __restrict__ c0, float* __restrict__ c1,
                  float* __restrict__ maskf)
{
    const int b = blockIdx.x;
    const int t = threadIdx.x;
    __shared__ float s0s[NU], s1s[NU];

    float k0v = kv[(long)b*KVW + t];
    float bkv = bk[t];
    for (int u = 0; u < NU; u++) {
        float q  = qry[((long)b*NU + u)*IKS + t];
        float p0 = q * k0v, p1 = q * bkv;
        #pragma unroll
        for (int off = 32; off > 0; off >>= 1) {
            p0 += __shfl_down(p0, off);
            p1 += __shfl_down(p1, off);
        }
        if (t == 0) { s0s[u] = p0 * 0.125f; s1s[u] = p1 * 0.125f; }
    }
    __syncthreads();
    if (t < NU) {
        int u = t;
        float su = s0s[u];
        int rank = 0;
        #pragma unroll
        for (int j = 0; j < NU; j++) {
            float sj = s0s[j];
            if (sj > su || (sj == su && j < u)) rank++;
        }
        float m = (rank < KTOP) ? 1.0f : 0.0f;
        float a = s0s[u], bb = s1s[u];
        float mx = fmaxf(a, bb);
        float e0 = expf(a - mx), e1 = expf(bb - mx);
        float p0 = e0 / (e0 + e1);
        c0[(long)b*NU + u]    = m * p0;
        c1[(long)b*NU + u]    = m * (1.0f - p0);
        maskf[(long)b*NU + u] = m;
    }
}

// ================= prep A for GRU GEMM (bf16, padded) =================
__global__ __launch_bounds__(256)
void prep_gruA_kernel(const float* __restrict__ kv, const float* __restrict__ bv,
                      const float* __restrict__ hs,
                      const float* __restrict__ c0, const float* __restrict__ c1,
                      u16* __restrict__ Ag)
{
    long id = (long)blockIdx.x * 256 + threadIdx.x;
    const long total = (long)NU * NB * (KGRU / 8);
    if (id >= total) return;
    int k8 = (int)(id % (KGRU / 8));
    int b  = (int)((id / (KGRU / 8)) % NB);
    int u  = (int)(id / ((long)(KGRU / 8) * NB));
    int k  = k8 * 8;
    u16 o[8];
    if (k < IVS) {
        float cv0 = c0[(long)b*NU + u], cv1 = c1[(long)b*NU + u];
        const float* kp = kv + (long)b*KVW + IKS + k;
        const float* bp = bv + k;
        #pragma unroll
        for (int i = 0; i < 8; i++) o[i] = f2bf(cv0*kp[i] + cv1*bp[i]);
    } else if (k >= HOFS && k < HOFS + NH) {
        const float* hp = hs + ((long)b*NU + u)*NH + (k - HOFS);
        #pragma unroll
        for (int i = 0; i < 8; i++) o[i] = f2bf(hp[i]);
    } else {
        #pragma unroll
        for (int i = 0; i < 8; i++) o[i] = 0;
    }
    *(short8*)&Ag[id * 8] = *(const short8*)o;
}

// ================= GRU MFMA (3 gates; block 128x32, 2-buf counted) =========
// wave tile 64x16; acc = 4 sets x 4 f32x4 = 64 AGPR -> 2 waves/SIMD.
// LDS: As[2][128*64] 32KB + Bs[2][96*64] 24KB = 56KB -> 2 blocks/CU.
__global__ __launch_bounds__(256, 2)
void gru_mfma_kernel(const u16* __restrict__ Ag, const u16* __restrict__ Wg,
                     const float* __restrict__ hs, u16* __restrict__ hnbf)
{
    const int u  = blockIdx.z;
    const int m0 = blockIdx.x * 128;
    const int n0 = blockIdx.y * 32;
    const int tid = threadIdx.x;
    const int wid = tid >> 6, lane = tid & 63;
    const int wm = wid >> 1, wn = wid & 1;
    const int lrow = lane & 15, lkq = lane >> 4;
    const int l8 = lane & 7, lr8 = lane >> 3;
    const int rsw = lrow & 7;                 // read-side XOR key

    __shared__ __align__(16) u16 As[2][128 * 64];
    __shared__ __align__(16) u16 Bs[2][96 * 64];

    const u16* Au = Ag + (long)u * NB * KGRU;
    const u16* Wu = Wg + (long)u * 3 * NGATE * KGRU;

    f32x4 aR[4], aI[4], aNX[4], aNH[4];
    #pragma unroll
    for (int m = 0; m < 4; m++) {
        aR[m] = (f32x4){0,0,0,0}; aI[m] = (f32x4){0,0,0,0};
        aNX[m] = (f32x4){0,0,0,0}; aNH[m] = (f32x4){0,0,0,0};
    }

// stage one BK=64 phase: 4 A + 3 B insts per wave (NST=7)
#define GSTAGE(BUF, PH_) do {                                                 \
        const long kk0 = (long)(PH_) * 64;                                    \
        _Pragma("unroll")                                                     \
        for (int i2 = 0; i2 < 4; i2++) {                                      \
            int rw = i2*32 + wid*8 + lr8;                                     \
            gl_lds16(Au + (long)(m0 + rw)*KGRU + kk0 + ((l8 ^ (rw & 7)) * 8), \
                     &As[BUF][(i2*32 + wid*8) * 64]);                         \
        }                                                                     \
        _Pragma("unroll")                                                     \
        for (int j2 = 0; j2 < 3; j2++) {                                      \
            int r = j2*32 + wid*8 + lr8;                                      \
            int g = r >> 5, rn = r & 31;                                      \
            gl_lds16(Wu + ((long)g*NGATE + n0 + rn)*KGRU + kk0                \
                        + ((l8 ^ (r & 7)) * 8),                               \
                     &Bs[BUF][(j2*32 + wid*8) * 64]);                         \
        }                                                                     \
    } while (0)

#define GCOMPUTE(BUF, PH_) do {                                               \
        __builtin_amdgcn_s_setprio(1);                                        \
        _Pragma("unroll")                                                     \
        for (int ks2 = 0; ks2 < 2; ks2++) {                                   \
            const int cofs = (((ks2*4 + lkq) ^ rsw) * 8);                     \
            short8 af[4], bR, bI, bN;                                         \
            _Pragma("unroll")                                                 \
            for (int m = 0; m < 4; m++)                                       \
                af[m] = *(const short8*)&As[BUF][(wm*64 + m*16 + lrow)*64 + cofs]; \
            {                                                                 \
                int nr = wn*16 + lrow;                                        \
                bR = *(const short8*)&Bs[BUF][(0*32 + nr)*64 + cofs];         \
                bI = *(const short8*)&Bs[BUF][(1*32 + nr)*64 + cofs];         \
                bN = *(const short8*)&Bs[BUF][(2*32 + nr)*64 + cofs];         \
            }                                                                 \
            _Pragma("unroll")                                                 \
            for (int m = 0; m < 4; m++) {                                     \
                aR[m] = __builtin_amdgcn_mfma_f32_16x16x32_bf16(af[m], bR, aR[m], 0, 0, 0); \
                aI[m] = __builtin_amdgcn_mfma_f32_16x16x32_bf16(af[m], bI, aI[m], 0, 0, 0); \
            }                                                                 \
            if (2*(PH_) + ks2 < HOFS/32) {                                    \
                _Pragma("unroll")                                             \
                for (int m = 0; m < 4; m++)                                   \
                    aNX[m] = __builtin_amdgcn_mfma_f32_16x16x32_bf16(af[m], bN, aNX[m], 0, 0, 0); \
            } else {                                                          \
                _Pragma("unroll")                                             \
                for (int m = 0; m < 4; m++)                                   \
                    aNH[m] = __builtin_amdgcn_mfma_f32_16x16x32_bf16(af[m], bN, aNH[m], 0, 0, 0); \
            }                                                                 \
        }                                                                     \
        __builtin_amdgcn_s_setprio(0);                                        \
    } while (0)

// phase: stage T+1 into other buf; wait own older stage; barrier; compute; drain lgkm; barrier
#define GPH(BUF, T, W) do {                                                   \
        if ((T) + 1 < 16) GSTAGE((BUF)^1, (T)+1);                             \
        WAITVM(W); SBAR();                                                    \
        GCOMPUTE(BUF, T);                                                     \
        WAITLG(); SBAR();                                                     \
    } while (0)

    GSTAGE(0, 0);
    for (int t = 0; t < 14; t += 2) { GPH(0, t, 7); GPH(1, t+1, 7); }
    GPH(0, 14, 7); GPH(1, 15, 0);
#undef GPH
#undef GCOMPUTE
#undef GSTAGE

    #pragma unroll
    for (int m = 0; m < 4; m++) {
        #pragma unroll
        for (int r = 0; r < 4; r++) {
            int row = m0 + wm*64 + m*16 + lkq*4 + r;   // b
            int col = n0 + wn*16 + lrow;               // c in [0,640)
            u16 ov = 0;
            if (col < NH) {
                float rg = 1.0f / (1.0f + expf(-aR[m][r]));
                float ig = 1.0f / (1.0f + expf(-aI[m][r]));
                float ng = tanhf(aNX[m][r] + rg * aNH[m][r]);
                float h  = hs[((long)row*NU + u)*NH + col];
                ov = f2bf(ng + ig * (h - ng));
            }
            hnbf[(long)u*NB*KH + (long)row*KH + col] = ov;
        }
    }
}

// ================= generic 128x128 bf16 MFMA GEMM (BK=64, 2-buf counted) ====
// EPI=0: f32 store; EPI=1: final out blend; EPI=2: bf16 store
template<int EPI>
__global__ __launch_bounds__(256, 2)
void mfgemm_kernel(const u16* __restrict__ A, long sAu, int lda,
                   const u16* __restrict__ Bw, long sBu, int ldb,
                   float* __restrict__ Cf, u16* __restrict__ C16,
                   long sCu, int ldc, int ksteps,      // ksteps in BK=64 units
                   const float* __restrict__ maskf,
                   const u16* __restrict__ hnbf,
                   const float* __restrict__ hs,
                   int bbase)
{
    const int u  = blockIdx.z;
    const int m0 = blockIdx.x * 128;
    const int n0 = blockIdx.y * 128;
    const int tid = threadIdx.x;
    const int wid = tid >> 6, lane = tid & 63;
    const int wm = wid >> 1, wn = wid & 1;
    const int lrow = lane & 15, lkq = lane >> 4;
    const int l8 = lane & 7, lr8 = lane >> 3;
    const int rsw = lrow & 7;

    __shared__ __align__(16) u16 As[2][128 * 64];
    __shared__ __align__(16) u16 Bs[2][128 * 64];

    const u16* Au = A + (long)u * sAu;
    const u16* Bu = Bw + (long)u * sBu;

    f32x4 acc[4][4];
    #pragma unroll
    for (int m = 0; m < 4; m++)
        #pragma unroll
        for (int n = 0; n < 4; n++) acc[m][n] = (f32x4){0,0,0,0};

// stage one BK=64 phase: 4 A + 4 B insts per wave (NST=8)
#define MSTAGE(BUF, KS) do {                                                  \
        const long kk0 = (long)(KS) * 64;                                     \
        _Pragma("unroll")                                                     \
        for (int i2 = 0; i2 < 4; i2++) {                                      \
            int rw = i2*32 + wid*8 + lr8;                                     \
            int co = ((l8 ^ (rw & 7)) * 8);                                   \
            gl_lds16(Au + (long)(m0 + rw)*lda + kk0 + co,                     \
                     &As[BUF][(i2*32 + wid*8) * 64]);                         \
            gl_lds16(Bu + (long)(n0 + rw)*ldb + kk0 + co,                     \
                     &Bs[BUF][(i2*32 + wid*8) * 64]);                         \
        }                                                                     \
    } while (0)

#define MCOMPUTE(BUF) do {                                                    \
        __builtin_amdgcn_s_setprio(1);                                        \
        _Pragma("unroll")                                                     \
        for (int ks2 = 0; ks2 < 2; ks2++) {                                   \
            const int cofs = (((ks2*4 + lkq) ^ rsw) * 8);                     \
            short8 af[4], bfr[4];                                             \
            _Pragma("unroll")                                                 \
            for (int m = 0; m < 4; m++)                                       \
                af[m] = *(const short8*)&As[BUF][(wm*64 + m*16 + lrow)*64 + cofs]; \
            _Pragma("unroll")                                                 \
            for (int n = 0; n < 4; n++)                                       \
                bfr[n] = *(const short8*)&Bs[BUF][(wn*64 + n*16 + lrow)*64 + cofs]; \
            _Pragma("unroll")                                                 \
            for (int m = 0; m < 4; m++)                                       \
                _Pragma("unroll")                                             \
                for (int n = 0; n < 4; n++)                                   \
                    acc[m][n] = __builtin_amdgcn_mfma_f32_16x16x32_bf16(af[m], bfr[n], acc[m][n], 0, 0, 0); \
        }                                                                     \
        __builtin_amdgcn_s_setprio(0);                                        \
    } while (0)

#define MPH(BUF, T, W) do {                                                   \
        if ((T) + 1 < ksteps) MSTAGE((BUF)^1, (T)+1);                         \
        WAITVM(W); SBAR();                                                    \
        MCOMPUTE(BUF);                                                        \
        WAITLG(); SBAR();                                                     \
    } while (0)

    MSTAGE(0, 0);
    int t = 0;
    for (; t + 2 < ksteps; t += 2) { MPH(0, t, 8); MPH(1, t+1, 8); }
    if (t + 2 == ksteps) { MPH(0, t, 8); MPH(1, t+1, 0); }
    else                 { MPH(0, t, 0); }   // odd tail (unused for our shapes)
#undef MPH
#undef MCOMPUTE
#undef MSTAGE

    #pragma unroll
    for (int m = 0; m < 4; m++) {
        #pragma unroll
        for (int r = 0; r < 4; r++) {
            int row = m0 + wm*64 + m*16 + lkq*4 + r;
            #pragma unroll
            for (int n = 0; n < 4; n++) {
                int col = n0 + wn*64 + n*16 + lrow;
                float v = acc[m][n][r];
                if (EPI == 0) {
                    Cf[(long)u*sCu + (long)row*ldc + col] = v;
                } else if (EPI == 2) {
                    C16[(long)u*sCu + (long)row*ldc + col] = f2bf(v);
                } else {
                    if (col < NH) {
                        int b = bbase + row;
                        long o = ((long)b*NU + u)*NH + col;
                        float mk = maskf[(long)b*NU + u];
                        float hv = bf2f(hnbf[(long)u*NB*KH + (long)b*KH + col]);
                        Cf[o] = (mk > 0.5f) ? (v + hv) : hs[o];
                    }
                }
            }
        }
    }
}

// ================= K7: attention weights =================
__global__ __launch_bounds__(64)
void attw_kernel(const float* __restrict__ qk, const float* __restrict__ maskf,
                 float* __restrict__ attw)
{
    const int bh = blockIdx.x;
    const int b = bh / NCH, h = bh % NCH;
    const int t = threadIdx.x;
    __shared__ float lg[NU][NU];

    if (t < NU * NU) {
        int uq = t / NU, un = t % NU;
        const float* qp = qk + ((long)b*NU + uq)*QKW + h*32;
        const float* kp = qk + ((long)b*NU + un)*QKW + 128 + h*32;
        float s = 0;
        #pragma unroll
        for (int i = 0; i < 32; i++) s = fmaf(qp[i], kp[i], s);
        lg[uq][un] = s * 0.17677669529663687f;
    }
    __syncthreads();
    if (t < NU) {
        int uq = t;
        float mx = -1e30f;
        #pragma unroll
        for (int n = 0; n < NU; n++) mx = fmaxf(mx, lg[uq][n]);
        float e[NU], se = 0;
        #pragma unroll
        for (int n = 0; n < NU; n++) { e[n] = expf(lg[uq][n] - mx); se += e[n]; }
        float m = maskf[(long)b*NU + uq];
        float inv = m / se;
        #pragma unroll
        for (int n = 0; n < NU; n++)
            attw[(((long)b*NCH + h)*NU + uq)*NU + n] = e[n] * inv;
    }
}

// ================= ctx = att @ v : each v read exactly once =================
__global__ __launch_bounds__(256)
void ctx2_kernel(const float* __restrict__ attw, const u16* __restrict__ v16,
                 u16* __restrict__ ctx16, int bbase)
{
    __shared__ float att_s[32][NCH * NU * NU];   // [bl][h*36+u*6+n] = 144
    const int c0 = blockIdx.x * 64;
    const int b0 = blockIdx.y * 32;
    const int tid = threadIdx.x;

    for (int i = tid; i < 32 * 144; i += 256) {
        int bl = i / 144, j = i % 144;
        att_s[bl][j] = attw[(long)(bbase + b0 + bl) * 144 + j];
    }
    __syncthreads();

    const int bl = tid >> 3;
    const int c  = c0 + (tid & 7) * 8;
    const long rowbase = (long)(b0 + bl) * NU;   // chunk-local

    if (c >= VW) {   // pad columns -> zero
        short8 z = {0,0,0,0,0,0,0,0};
        #pragma unroll
        for (int u = 0; u < NU; u++)
            *(short8*)&ctx16[(rowbase + u) * VN + c] = z;
        return;
    }
    const int h = c / CVS;
    const float* aw = &att_s[bl][h * 36];

    float acc[NU][8] = {};
    #pragma unroll
    for (int n = 0; n < NU; n++) {
        short8 vv = *(const short8*)&v16[(rowbase + n) * VN + c];
        float vf[8];
        #pragma unroll
        for (int i = 0; i < 8; i++) vf[i] = bf2f((u16)vv[i]);
        #pragma unroll
        for (int u = 0; u < NU; u++) {
            float a = aw[u * 6 + n];
            #pragma unroll
            for (int i = 0; i < 8; i++) acc[u][i] = fmaf(a, vf[i], acc[u][i]);
        }
    }
    #pragma unroll
    for (int u = 0; u < NU; u++) {
        short8 o;
        #pragma unroll
        for (int i = 0; i < 8; i++) o[i] = (short)f2bf(acc[u][i]);
        *(short8*)&ctx16[(rowbase + u) * VN + c] = o;
    }
}

// ================= host launcher =================
extern "C" void kernel_launch(void* const* d_in, const int* in_sizes, int n_in,
                              void* d_out, int out_size, void* d_ws, size_t ws_size,
                              hipStream_t stream)
{
    const float* x    = (const float*)d_in[0];
    const float* hs   = (const float*)d_in[1];
    const float* Wk   = (const float*)d_in[2];
    const float* bk   = (const float*)d_in[3];
    const float* Wv   = (const float*)d_in[4];
    const float* bv   = (const float*)d_in[5];
    const float* Wq   = (const float*)d_in[6];
    const float* x2h  = (const float*)d_in[7];
    const float* h2h  = (const float*)d_in[8];
    const float* Wq_  = (const float*)d_in[9];
    const float* Wk_  = (const float*)d_in[10];
    const float* Wv_  = (const float*)d_in[11];
    const float* Wout = (const float*)d_in[12];
    float* out = (float*)d_out;
    float* ws  = (float*)d_ws;

    float* kv    = ws + OFF_KV;
    float* qry   = ws + OFF_QRY;
    float* c0b   = ws + OFF_C0;
    float* c1b   = ws + OFF_C1;
    float* maskf = ws + OFF_MASK;
    float* qk    = ws + OFF_QK;
    float* attw  = ws + OFF_ATTW;
    u16*   hnbf  = (u16*)(ws + OFF_HNBF);
    u16*   wqk   = (u16*)(ws + OFF_WQK);
    u16*   wv    = (u16*)(ws + OFF_WV);
    u16*   wout  = (u16*)(ws + OFF_WOUT);
    u16*   wgru  = (u16*)(ws + OFF_WGRU);
    u16*   agru  = (u16*)(ws + OFF_AGRU);
    u16*   vbuf16 = (u16*)(ws + OFF_VBUF);
    u16*   ctx16  = (u16*)(ws + OFF_CTXB);

    // 1) weight conversions/transposes (k-pads zero-written by wtrans)
    wtrans_kernel<<<dim3(20, 4, NU), 256, 0, stream>>>(
        Wq_, (long)NH*128, 128, 0, NH, 128, wqk, (long)QKW*KH, KH, 0, 0);
    wtrans_kernel<<<dim3(20, 4, NU), 256, 0, stream>>>(
        Wk_, (long)NH*128, 128, 0, NH, 128, wqk, (long)QKW*KH, KH, 128, 0);
    wtrans_kernel<<<dim3(20, 75, NU), 256, 0, stream>>>(
        Wv_, (long)NH*VW, VW, 0, NH, VW, wv, (long)VN*KH, KH, 0, 0);
    wtrans_kernel<<<dim3(76, 19, NU), 256, 0, stream>>>(
        Wout, (long)VW*NH, NH, 0, VW, NH, wout, (long)NGATE*VN, VN, 0, 0);
    for (int g = 0; g < 3; g++) {
        wtrans_kernel<<<dim3(13, 19, NU), 256, 0, stream>>>(
            x2h, (long)IVS*3*NH, 3*NH, g*NH, IVS, NH,
            wgru + (long)g*NGATE*KGRU, (long)3*NGATE*KGRU, KGRU, 0, 0);
        wtrans_kernel<<<dim3(19, 19, NU), 256, 0, stream>>>(
            h2h, (long)NH*3*NH, 3*NH, g*NH, NH, NH,
            wgru + (long)g*NGATE*KGRU, (long)3*NGATE*KGRU, KGRU, 0, HOFS);
    }

    // 2) f32 front-end
    gemm_kv_kernel<<<dim3(NB/64, (KVW+63)/64), 256, 0, stream>>>(x, Wk, bk, Wv, bv, kv);
    gemm_qry_kernel<<<dim3(NB/64, 1, NU), 256, 0, stream>>>(hs, Wq, qry);
    score_kernel<<<NB, 64, 0, stream>>>(qry, kv, bk, c0b, c1b, maskf);

    // 3) GRU A prep + GRU MFMA
    {
        long total = (long)NU * NB * (KGRU/8);
        prep_gruA_kernel<<<(unsigned)((total + 255)/256), 256, 0, stream>>>(
            kv, bv, hs, c0b, c1b, agru);
    }
    gru_mfma_kernel<<<dim3(NB/128, NGATE/32, NU), 256, 0, stream>>>(agru, wgru, hs, hnbf);

    // 4) qk projection (MFMA) + attention weights
    mfgemm_kernel<0><<<dim3(NB/128, QKW/128, NU), 256, 0, stream>>>(
        hnbf, (long)NB*KH, KH, wqk, (long)QKW*KH, KH,
        qk, nullptr, (long)QKW, NU*QKW, KH/64, nullptr, nullptr, nullptr, 0);
    attw_kernel<<<NB*NCH, 64, 0, stream>>>(qk, maskf, attw);

    // 5) chunked v / ctx / out  (BC=1024, 4 chunks)
    for (int ch = 0; ch < NCHUNK; ch++) {
        mfgemm_kernel<2><<<dim3(BC/128, VN/128, NU), 256, 0, stream>>>(
            hnbf + (long)ch*BC*KH, (long)NB*KH, KH, wv, (long)VN*KH, KH,
            nullptr, vbuf16, (long)VN, NU*VN, KH/64, nullptr, nullptr, nullptr, 0);
        ctx2_kernel<<<dim3(VN/64, BC/32), 256, 0, stream>>>(
            attw, vbuf16, ctx16, ch*BC);
        mfgemm_kernel<1><<<dim3(BC/128, NGATE/128, NU), 256, 0, stream>>>(
            ctx16, (long)VN, NU*VN, wout, (long)NGATE*VN, VN,
            out, nullptr, 0, 0, VN/64, maskf, hnbf, hs, ch*BC);
    }
}